// Round 28
// baseline (195.694 us; speedup 1.0000x reference)
//
#include <hip/hip_runtime.h>
#include <math.h>

typedef unsigned short u16;
typedef __attribute__((ext_vector_type(4))) float f32x4;
typedef __attribute__((ext_vector_type(16))) float f32x16;
typedef __attribute__((ext_vector_type(4))) unsigned short u16x4;
typedef __attribute__((ext_vector_type(8))) short bf16x8;
typedef __attribute__((ext_vector_type(8))) unsigned short u16x8;

#define LOG2E 1.4426950408889634f
#define QSCALE (0.08838834764831845f * LOG2E)   // 1/sqrt(128) * log2(e)

__device__ __forceinline__ u16 f2bf(float f) {
  union { float f; unsigned u; } v; v.f = f;
  unsigned r = (v.u + 0x7fff + ((v.u >> 16) & 1)) >> 16;
  return (u16)r;
}
__device__ __forceinline__ float bf2f(u16 u) {
  union { unsigned u; float f; } v; v.u = ((unsigned)u) << 16; return v.f;
}
__device__ __forceinline__ void stor(float* C, size_t i, float v) { C[i] = v; }
__device__ __forceinline__ void stor(u16* C, size_t i, float v) { C[i] = f2bf(v); }

__device__ __forceinline__ unsigned cvtpk(float a, float b) {
  unsigned r;
  asm("v_cvt_pk_bf16_f32 %0, %1, %2" : "=v"(r) : "v"(a), "v"(b));
  return r;
}
// swap: a.hi-lanes <-> b.lo-lanes. Operands MUST be distinct values
// (same-value copies may share a register -> self-swap corruption, R17 bug).
__device__ __forceinline__ void plswap(unsigned &a, unsigned &b) {
  asm volatile("v_permlane32_swap_b32 %0, %1" : "+v"(a), "+v"(b));
}

// ---------------------------------------------------------------------------
// Fused f32 -> bf16 conversion of TWO arrays in one launch.
// ---------------------------------------------------------------------------
__global__ void conv2_f32_bf16(const float* __restrict__ a, u16* __restrict__ da,
                               int nblkA, const float* __restrict__ b,
                               u16* __restrict__ db) {
  int blk = blockIdx.x;
  const float* src;
  u16* dst;
  int base;
  if (blk < nblkA) { src = a; dst = da; base = blk; }
  else             { src = b; dst = db; base = blk - nblkA; }
  int i = (base * 256 + threadIdx.x) * 4;
  f32x4 v = *(const f32x4*)(src + i);
  u16x4 o;
#pragma unroll
  for (int j = 0; j < 4; ++j) o[j] = f2bf(v[j]);
  *(u16x4*)(dst + i) = o;
}

__global__ void conv_f32_bf16(const float* __restrict__ src, u16* __restrict__ dst) {
  int i = (blockIdx.x * blockDim.x + threadIdx.x) * 4;
  f32x4 v = *(const f32x4*)(src + i);
  u16x4 o;
#pragma unroll
  for (int j = 0; j < 4; ++j) o[j] = f2bf(v[j]);
  *(u16x4*)(dst + i) = o;
}

// ---------------------------------------------------------------------------
// Pipelined 128x128 GEMM (T3/T4 schedule): BK=64, 4 waves (2x2), dbuf 64KB
// LDS, depth-2 prefetch, counted vmcnt(8), both-sides XOR swizzle.
// ---------------------------------------------------------------------------
template <typename TOUT>
__global__ __launch_bounds__(256, 1)
void gemm128p_bt(const u16* __restrict__ A, const u16* __restrict__ B,
                 TOUT* __restrict__ C, int M, int N, int K) {
  __shared__ __align__(16) char smem[65536];    // 2 slots x (A 16KB + B 16KB)
  const int tid  = threadIdx.x;
  const int lane = tid & 63;
  const int wid  = tid >> 6;        // 0..3
  const int wr = wid >> 1, wc = wid & 1;
  const int fr = lane & 15, fq = lane >> 4;

  const int nwg = gridDim.x;
  const int wg  = (blockIdx.x & 7) * (nwg >> 3) + (blockIdx.x >> 3);
  const int nrt = M >> 7;
  const int rt  = wg % nrt, ct = wg / nrt;
  const int row0 = rt * 128, col0 = ct * 128;
  const int nt = K >> 6;

#define STAGE128(base, kt)                                                      \
  {                                                                             \
    _Pragma("unroll")                                                           \
    for (int j = 0; j < 4; ++j) {                                               \
      int c   = tid + j * 256;                                                  \
      int row = c >> 3;                                                         \
      int ke  = (((c & 7) ^ (row & 7)) * 8);                                    \
      const u16* sA = A + (size_t)(row0 + row) * K + (kt) * 64 + ke;            \
      __builtin_amdgcn_global_load_lds(                                         \
          (const __attribute__((address_space(1))) void*)sA,                    \
          (__attribute__((address_space(3))) void*)((base) + c * 16), 16, 0, 0);\
      const u16* sB = B + (size_t)(col0 + row) * K + (kt) * 64 + ke;            \
      __builtin_amdgcn_global_load_lds(                                         \
          (const __attribute__((address_space(1))) void*)sB,                    \
          (__attribute__((address_space(3))) void*)((base) + 16384 + c * 16), 16, 0, 0);\
    }                                                                           \
  }

  STAGE128(smem, 0);
  STAGE128(smem + 32768, 1);
  asm volatile("s_waitcnt vmcnt(8)" ::: "memory");   // tile 0 landed
  __builtin_amdgcn_s_barrier();
  __builtin_amdgcn_sched_barrier(0);

  f32x4 acc[4][4] = {};

  for (int t = 0; t < nt; ++t) {
    char* slot = smem + (t & 1) * 32768;

    bf16x8 af[4][2], bf[4][2];
#pragma unroll
    for (int mf = 0; mf < 4; ++mf)
#pragma unroll
      for (int kk = 0; kk < 2; ++kk) {
        int row = wr * 64 + mf * 16 + fr;
        int off = row * 128 + ((kk * 64 + fq * 16) ^ ((row & 7) << 4));
        af[mf][kk] = *(const bf16x8*)(slot + off);
      }
#pragma unroll
    for (int nf = 0; nf < 4; ++nf)
#pragma unroll
      for (int kk = 0; kk < 2; ++kk) {
        int row = wc * 64 + nf * 16 + fr;
        int off = row * 128 + ((kk * 64 + fq * 16) ^ ((row & 7) << 4));
        bf[nf][kk] = *(const bf16x8*)(slot + 16384 + off);
      }
    asm volatile("s_waitcnt lgkmcnt(0)" ::: "memory");
    __builtin_amdgcn_sched_barrier(0);
    __builtin_amdgcn_s_barrier();
    __builtin_amdgcn_sched_barrier(0);

    if (t + 2 < nt) STAGE128(slot, t + 2);
    __builtin_amdgcn_sched_barrier(0);

    __builtin_amdgcn_s_setprio(1);
#pragma unroll
    for (int kk = 0; kk < 2; ++kk)
#pragma unroll
      for (int mf = 0; mf < 4; ++mf)
#pragma unroll
        for (int nf = 0; nf < 4; ++nf)
          acc[mf][nf] = __builtin_amdgcn_mfma_f32_16x16x32_bf16(
              af[mf][kk], bf[nf][kk], acc[mf][nf], 0, 0, 0);
    __builtin_amdgcn_s_setprio(0);

    if (t + 2 < nt) {
      asm volatile("s_waitcnt vmcnt(8)" ::: "memory");
    } else {
      asm volatile("s_waitcnt vmcnt(0)" ::: "memory");
    }
    __builtin_amdgcn_s_barrier();
    __builtin_amdgcn_sched_barrier(0);
  }
#undef STAGE128

#pragma unroll
  for (int mf = 0; mf < 4; ++mf)
#pragma unroll
    for (int nf = 0; nf < 4; ++nf) {
      int row = row0 + wr * 64 + mf * 16 + fq * 4;
      int col = col0 + wc * 64 + nf * 16 + fr;
#pragma unroll
      for (int r = 0; r < 4; ++r)
        stor(C, (size_t)(row + r) * N + col, acc[mf][nf][r]);
    }
}

// ---------------------------------------------------------------------------
// RoPE in-place on q,k parts of qkv. Q pre-scaled by QSCALE.
// ---------------------------------------------------------------------------
__global__ void rope_qk(u16* qkv) {
  int idx = blockIdx.x * blockDim.x + threadIdx.x;
  int i4 = idx & 15;
  int h  = (idx >> 4) & 15;
  int t  = (idx >> 8) & 1;
  int s  = idx >> 9;
  u16* p = qkv + (size_t)s * 6144 + t * 2048 + h * 128 + i4 * 8;
  const float post = t ? 1.0f : QSCALE;
  u16x8 v = *(const u16x8*)p;
  u16x8 w;
#pragma unroll
  for (int j = 0; j < 4; ++j) {
    int i = i4 * 4 + j;
    float inv = exp2f(-(float)i * 0.2076205059304601f);  // 10000^(-i/64)
    float ang = (float)s * inv;
    float sn, cs;
    sincosf(ang, &sn, &cs);
    float e = bf2f(v[2 * j]);
    float o = bf2f(v[2 * j + 1]);
    w[2 * j]     = f2bf((e * cs - o * sn) * post);
    w[2 * j + 1] = f2bf((e * sn + o * cs) * post);
  }
  *(u16x8*)p = w;
}

// ---------------------------------------------------------------------------
// Fused repack of V and K into per-(head, kv-tile) 8KB tiles, one launch.
// ---------------------------------------------------------------------------
__global__ void repack_kv(const u16* __restrict__ qkv, u16* __restrict__ vt2,
                          u16* __restrict__ kt2) {
  if (blockIdx.y < 64) {
    __shared__ u16 tile[32][33];
    int s0 = blockIdx.x * 32, c0 = blockIdx.y * 32;
    int tx = threadIdx.x & 31, ty = threadIdx.x >> 5;  // 32 x 8
#pragma unroll
    for (int i = ty; i < 32; i += 8)
      tile[i][tx] = qkv[(size_t)(s0 + i) * 6144 + 4096 + c0 + tx];
    __syncthreads();
    int t = s0 >> 5;
#pragma unroll
    for (int i = ty; i < 32; i += 8) {
      int col = c0 + i;                 // h*128 + d
      int h = col >> 7, d = col & 127;
      int slot = ((d >> 3) << 5) + ((tx >> 3) << 3) + (d & 7);
      vt2[((size_t)(h * 64 + t)) * 4096 + slot * 8 + (tx & 7)] = tile[tx][i];
    }
  } else {
    int t = blockIdx.x, h = blockIdx.y - 64;
    int j = threadIdx.x >> 3;        // kv row 0..31
    int c = threadIdx.x & 7;         // d-chunk of 16 u16
    const u16* src = qkv + (size_t)(t * 32 + j) * 6144 + 2048 + h * 128 + c * 16;
    u16* dst = kt2 + ((size_t)(h * 64 + t)) * 4096 + c * 512 + j * 16;
    *(u16x8*)dst       = *(const u16x8*)src;
    *(u16x8*)(dst + 8) = *(const u16x8*)(src + 8);
  }
}

// ---------------------------------------------------------------------------
// Causal flash attention: 4-wave FLAT blocks, all-direct K/V, LPT order.
// KV-loop UNROLLED x2: per iteration, V for tiles t0 and t0+4 issued at top
// (16 loads in flight); K(t1) issued during tile0's softmax/PV so its L2
// latency hides under VALU+MFMA. Math identical to the proven single-tile
// body executed twice; tile1 guarded by wave-uniform act1 with load pointers
// clamped in-bounds. __launch_bounds__(256,1): VGPR cap 256 (no spill).
// ---------------------------------------------------------------------------
__global__ __launch_bounds__(256, 1)
void attn_fwd(const u16* __restrict__ qkv, const u16* __restrict__ kt2,
              const u16* __restrict__ vt2, u16* __restrict__ ao) {
  const int f    = blockIdx.y * 64 + blockIdx.x;
  const int h    = ((f & 7) << 1) | ((f >> 3) & 1);  // 2 heads per XCD
  const int tile = 63 - (f >> 4);                     // LPT: longest first
  const int tid  = threadIdx.x;
  const int lane = tid & 63;
  const int wid  = tid >> 6;        // 0..3 = kv-split slot
  const int l31  = lane & 31;
  const int hh   = lane >> 5;
  const int q0 = tile * 32;

  __shared__ __align__(16) char smem[17408];
  char* bufQ = smem;                                       // 8KB, loop phase
  float (*Obuf)[128] = (float(*)[128])smem;                // overlay post-loop (16KB)
  float (*mls)[32][2] = (float(*)[32][2])(smem + 16384);   // overlay post-loop (1KB)

  const char* qkvB = (const char*)qkv;
  const char* ktH = (const char*)kt2 + (size_t)h * 64 * 8192;
  const char* vtH = (const char*)vt2 + (size_t)h * 64 * 8192;

  // ---- prologue: stage shared Q (2 instrs/wave) ----
#pragma unroll
  for (int kk = 0; kk < 2; ++kk) {
    int k = wid * 2 + kk;
    int s = k * 64 + lane;
    int row = ((s >> 7) << 3) | (s & 7);
    int c = (s >> 3) & 15;
    const char* src = qkvB + (size_t)(q0 + row) * 12288 + h * 256 + c * 16;
    __builtin_amdgcn_global_load_lds(
        (const __attribute__((address_space(1))) void*)src,
        (__attribute__((address_space(3))) void*)(bufQ + k * 1024 + lane * 16), 16, 0, 0);
  }
  __syncthreads();   // Q ready

  f32x16 oacc[4] = {};              // q=(r&3)+8*(r>>2)+4*hh, d=32c+l31
  float M = -1e30f, L = 0.f;

  const int qkBase = ((l31 >> 3) << 11) + (hh << 7) + ((l31 & 7) << 4);  // Q: + s*256
  const int vBase  = ((l31 >> 3) << 9)  + (hh << 7) + ((l31 & 7) << 4);  // V: + c*2048 + tt*256
  const int kBase  = l31 * 32 + hh * 16;                                  // K: + s*1024

  for (int t0 = wid; t0 <= tile; t0 += 8) {
    const int t1 = t0 + 4;
    const bool act1 = (t1 <= tile);
    const int t1c = act1 ? t1 : t0;           // clamped (in-bounds, discarded)
    const char* kt0 = ktH + (size_t)t0 * 8192;
    const char* vt0 = vtH + (size_t)t0 * 8192;
    const char* kt1 = ktH + (size_t)t1c * 8192;
    const char* vt1 = vtH + (size_t)t1c * 8192;

    // V fragments for BOTH tiles (16 loads in flight)
    bf16x8 vf0[4][2], vf1[4][2];
#pragma unroll
    for (int c = 0; c < 4; ++c)
#pragma unroll
      for (int tt = 0; tt < 2; ++tt) {
        vf0[c][tt] = *(const bf16x8*)(vt0 + vBase + c * 2048 + tt * 256);
        vf1[c][tt] = *(const bf16x8*)(vt1 + vBase + c * 2048 + tt * 256);
      }

    // ======== tile 0 ========
    f32x16 sc = {};
    {
      bf16x8 ka[4], qa[4];
#pragma unroll
      for (int s = 0; s < 4; ++s) {
        ka[s] = *(const bf16x8*)(kt0 + kBase + s * 1024);
        qa[s] = *(const bf16x8*)(bufQ + qkBase + s * 256);
      }
      __builtin_amdgcn_s_setprio(1);
#pragma unroll
      for (int s = 0; s < 4; ++s)
        sc = __builtin_amdgcn_mfma_f32_32x32x16_bf16(ka[s], qa[s], sc, 0, 0, 0);
      __builtin_amdgcn_s_setprio(0);
#pragma unroll
      for (int s = 0; s < 4; ++s) {
        ka[s] = *(const bf16x8*)(kt0 + kBase + (s + 4) * 1024);
        qa[s] = *(const bf16x8*)(bufQ + qkBase + (s + 4) * 256);
      }
      __builtin_amdgcn_s_setprio(1);
#pragma unroll
      for (int s = 0; s < 4; ++s)
        sc = __builtin_amdgcn_mfma_f32_32x32x16_bf16(ka[s], qa[s], sc, 0, 0, 0);
      __builtin_amdgcn_s_setprio(0);
    }

    // prefetch K(t1) into registers -- latency hides under softmax0/PV0
    bf16x8 ka1[8];
#pragma unroll
    for (int s = 0; s < 8; ++s)
      ka1[s] = *(const bf16x8*)(kt1 + kBase + s * 1024);

    if (t0 == tile) {
#pragma unroll
      for (int r = 0; r < 16; ++r) {
        int kv = (r & 3) + 8 * (r >> 2) + 4 * hh;
        if (kv > l31) sc[r] = -1e30f;
      }
    }

    {
      float pm = fmaxf(fmaxf(fmaxf(sc[0], sc[1]), fmaxf(sc[2], sc[3])),
                       fmaxf(fmaxf(sc[4], sc[5]), fmaxf(sc[6], sc[7])));
      float pm2 = fmaxf(fmaxf(fmaxf(sc[8], sc[9]), fmaxf(sc[10], sc[11])),
                        fmaxf(fmaxf(sc[12], sc[13]), fmaxf(sc[14], sc[15])));
      pm = fmaxf(pm, pm2);
      pm = fmaxf(pm, __shfl_xor(pm, 32, 64));
      bool defer = (pm <= M + 8.0f);
      if (!__all(defer)) {
        float Mn = fmaxf(M, pm);
        float corr = exp2f(M - Mn);
        M = Mn;
        L *= corr;
#pragma unroll
        for (int r = 0; r < 16; ++r) {
          float cr = __shfl(corr, (r & 3) + 8 * (r >> 2) + 4 * hh, 64);
#pragma unroll
          for (int c = 0; c < 4; ++c) oacc[c][r] *= cr;
        }
      }
#pragma unroll
      for (int r = 0; r < 16; ++r) sc[r] = exp2f(sc[r] - M);
      float rs = ((sc[0] + sc[1]) + (sc[2] + sc[3])) + ((sc[4] + sc[5]) + (sc[6] + sc[7]))
               + ((sc[8] + sc[9]) + (sc[10] + sc[11])) + ((sc[12] + sc[13]) + (sc[14] + sc[15]));
      rs += __shfl_xor(rs, 32, 64);
      L += rs;
#pragma unroll
      for (int tt = 0; tt < 2; ++tt) {
        unsigned A0 = cvtpk(sc[8 * tt + 0], sc[8 * tt + 1]);
        unsigned A1 = cvtpk(sc[8 * tt + 2], sc[8 * tt + 3]);
        unsigned B0 = cvtpk(sc[8 * tt + 4], sc[8 * tt + 5]);
        unsigned B1 = cvtpk(sc[8 * tt + 6], sc[8 * tt + 7]);
        plswap(A0, B0);
        plswap(A1, B1);
        union { unsigned w[4]; bf16x8 v; } pa;
        pa.w[0] = A0; pa.w[1] = A1; pa.w[2] = B0; pa.w[3] = B1;
        __builtin_amdgcn_s_setprio(1);
#pragma unroll
        for (int c = 0; c < 4; ++c)
          oacc[c] = __builtin_amdgcn_mfma_f32_32x32x16_bf16(pa.v, vf0[c][tt], oacc[c], 0, 0, 0);
        __builtin_amdgcn_s_setprio(0);
      }
    }

    // ======== tile 1 (guarded, wave-uniform) ========
    if (act1) {
      f32x16 sc1 = {};
      {
        bf16x8 qa[8];
#pragma unroll
        for (int s = 0; s < 8; ++s)
          qa[s] = *(const bf16x8*)(bufQ + qkBase + s * 256);
        __builtin_amdgcn_s_setprio(1);
#pragma unroll
        for (int s = 0; s < 8; ++s)
          sc1 = __builtin_amdgcn_mfma_f32_32x32x16_bf16(ka1[s], qa[s], sc1, 0, 0, 0);
        __builtin_amdgcn_s_setprio(0);
      }

      if (t1 == tile) {
#pragma unroll
        for (int r = 0; r < 16; ++r) {
          int kv = (r & 3) + 8 * (r >> 2) + 4 * hh;
          if (kv > l31) sc1[r] = -1e30f;
        }
      }

      float pm = fmaxf(fmaxf(fmaxf(sc1[0], sc1[1]), fmaxf(sc1[2], sc1[3])),
                       fmaxf(fmaxf(sc1[4], sc1[5]), fmaxf(sc1[6], sc1[7])));
      float pm2 = fmaxf(fmaxf(fmaxf(sc1[8], sc1[9]), fmaxf(sc1[10], sc1[11])),
                        fmaxf(fmaxf(sc1[12], sc1[13]), fmaxf(sc1[14], sc1[15])));
      pm = fmaxf(pm, pm2);
      pm = fmaxf(pm, __shfl_xor(pm, 32, 64));
      bool defer = (pm <= M + 8.0f);
      if (!__all(defer)) {
        float Mn = fmaxf(M, pm);
        float corr = exp2f(M - Mn);
        M = Mn;
        L *= corr;
#pragma unroll
        for (int r = 0; r < 16; ++r) {
          float cr = __shfl(corr, (r & 3) + 8 * (r >> 2) + 4 * hh, 64);
#pragma unroll
          for (int c = 0; c < 4; ++c) oacc[c][r] *= cr;
        }
      }
#pragma unroll
      for (int r = 0; r < 16; ++r) sc1[r] = exp2f(sc1[r] - M);
      float rs = ((sc1[0] + sc1[1]) + (sc1[2] + sc1[3])) + ((sc1[4] + sc1[5]) + (sc1[6] + sc1[7]))
               + ((sc1[8] + sc1[9]) + (sc1[10] + sc1[11])) + ((sc1[12] + sc1[13]) + (sc1[14] + sc1[15]));
      rs += __shfl_xor(rs, 32, 64);
      L += rs;
#pragma unroll
      for (int tt = 0; tt < 2; ++tt) {
        unsigned A0 = cvtpk(sc1[8 * tt + 0], sc1[8 * tt + 1]);
        unsigned A1 = cvtpk(sc1[8 * tt + 2], sc1[8 * tt + 3]);
        unsigned B0 = cvtpk(sc1[8 * tt + 4], sc1[8 * tt + 5]);
        unsigned B1 = cvtpk(sc1[8 * tt + 6], sc1[8 * tt + 7]);
        plswap(A0, B0);
        plswap(A1, B1);
        union { unsigned w[4]; bf16x8 v; } pa;
        pa.w[0] = A0; pa.w[1] = A1; pa.w[2] = B0; pa.w[3] = B1;
        __builtin_amdgcn_s_setprio(1);
#pragma unroll
        for (int c = 0; c < 4; ++c)
          oacc[c] = __builtin_amdgcn_mfma_f32_32x32x16_bf16(pa.v, vf1[c][tt], oacc[c], 0, 0, 0);
        __builtin_amdgcn_s_setprio(0);
      }
    }
  }

  // ---- overlay handoff: loop done -> Q buffer dead ----
  __syncthreads();
  if (hh == 0) { mls[wid][l31][0] = M; mls[wid][l31][1] = L; }
  __syncthreads();

  // flash merge over the 4 kv-split partials
  for (int w = 0; w < 4; ++w) {
    if (wid == w) {
#pragma unroll
      for (int r = 0; r < 16; ++r) {
        int q = (r & 3) + 8 * (r >> 2) + 4 * hh;
        float m_own = mls[wid][q][0];   // per-row max from LDS (R20 fix)
        float Mg = fmaxf(fmaxf(mls[0][q][0], mls[1][q][0]),
                         fmaxf(mls[2][q][0], mls[3][q][0]));
        float s = exp2f(m_own - Mg);
#pragma unroll
        for (int c = 0; c < 4; ++c) {
          float v = oacc[c][r] * s;
          if (w == 0) Obuf[q][32 * c + l31] = v;
          else        Obuf[q][32 * c + l31] += v;
        }
      }
    }
    __syncthreads();
  }

  // write-out: wave wid normalizes+stores rows wid*8 .. wid*8+7
#pragma unroll
  for (int rr = 0; rr < 8; ++rr) {
    int row = wid * 8 + rr;
    float Mg = fmaxf(fmaxf(mls[0][row][0], mls[1][row][0]),
                     fmaxf(mls[2][row][0], mls[3][row][0]));
    float lt = 0.f;
#pragma unroll
    for (int w2 = 0; w2 < 4; ++w2)
      lt += exp2f(mls[w2][row][0] - Mg) * mls[w2][row][1];
    float inv = 1.0f / lt;
    float v0 = Obuf[row][lane * 2]     * inv;
    float v1 = Obuf[row][lane * 2 + 1] * inv;
    unsigned pack = (unsigned)f2bf(v0) | ((unsigned)f2bf(v1) << 16);
    *(unsigned*)&ao[(size_t)(q0 + row) * 2048 + h * 128 + lane * 2] = pack;
  }
}

// ---------------------------------------------------------------------------
extern "C" void kernel_launch(void* const* d_in, const int* in_sizes, int n_in,
                              void* d_out, int out_size, void* d_ws, size_t ws_size,
                              hipStream_t stream) {
  const float* x     = (const float*)d_in[0];   // 2048 x 2048 f32
  const float* w_qkv = (const float*)d_in[1];   // 6144 x 2048 f32
  const float* w_out = (const float*)d_in[2];   // 2048 x 2048 f32
  float* out = (float*)d_out;                   // 2048 x 2048 f32
  const int S = 2048, H = 2048, O3 = 6144;

  // workspace (u16 elems), peak 58.8 MB with aliasing:
  u16* qkv     = (u16*)d_ws;                    // S*O3 = 25.2 MB
  u16* x_bf    = qkv + (size_t)S * O3;          //  8.4 MB
  u16* wqkv_bf = x_bf + (size_t)S * H;          // 25.2 MB region
  u16* ao      = x_bf;                          // alias (x_bf dead after GEMM1)
  u16* vt2     = wqkv_bf;                       // alias: 8.4 MB
  u16* kt2     = wqkv_bf + (size_t)H * S;       // alias: 8.4 MB
  u16* wout_bf = wqkv_bf + 2 * (size_t)H * S;   // alias: 8.4 MB (= 25.2 total)

  // 1. convert x and w_qkv to bf16 (single fused launch)
  conv2_f32_bf16<<<(S * H) / 1024 + (O3 * H) / 1024, 256, 0, stream>>>(
      x, x_bf, (S * H) / 1024, w_qkv, wqkv_bf);
  // 2. qkv = x @ w_qkv^T  (M=2048, N=6144, K=2048) -- pipelined 128^2, 768 blocks
  gemm128p_bt<u16><<<(S / 128) * (O3 / 128), 256, 0, stream>>>(x_bf, wqkv_bf, qkv, S, O3, H);
  // 3. RoPE on q,k in place (q pre-scaled by QSCALE)
  rope_qk<<<(S * 2 * 16 * 16) / 256, 256, 0, stream>>>(qkv);
  // 4. repack V and K into per-(h,t) tiles (single fused launch)
  repack_kv<<<dim3(64, 80), 256, 0, stream>>>(qkv, vt2, kt2);
  // 5. convert w_out (into region freed after GEMM1)
  conv_f32_bf16<<<(S * H) / 1024, 256, 0, stream>>>(w_out, wout_bf);
  // 6. causal flash attention (4-wave flat blocks, 2x-unrolled kv loop) -> ao
  attn_fwd<<<dim3(64, 16), 256, 0, stream>>>(qkv, kt2, vt2, ao);
  // 7. out = ao @ w_out^T  (M=2048, N=2048, K=2048) -- pipelined 128^2, f32 out
  gemm128p_bt<float><<<(S / 128) * (H / 128), 256, 0, stream>>>(ao, wout_bf, out, S, H, H);
}

// Round 29
// 167.108 us; speedup vs baseline: 1.1711x; 1.1711x over previous
//
#include <hip/hip_runtime.h>
#include <math.h>

typedef unsigned short u16;
typedef __attribute__((ext_vector_type(4))) float f32x4;
typedef __attribute__((ext_vector_type(16))) float f32x16;
typedef __attribute__((ext_vector_type(4))) unsigned short u16x4;
typedef __attribute__((ext_vector_type(8))) short bf16x8;
typedef __attribute__((ext_vector_type(8))) unsigned short u16x8;

#define LOG2E 1.4426950408889634f
#define QSCALE (0.08838834764831845f * LOG2E)   // 1/sqrt(128) * log2(e)

__device__ __forceinline__ u16 f2bf(float f) {
  union { float f; unsigned u; } v; v.f = f;
  unsigned r = (v.u + 0x7fff + ((v.u >> 16) & 1)) >> 16;
  return (u16)r;
}
__device__ __forceinline__ float bf2f(u16 u) {
  union { unsigned u; float f; } v; v.u = ((unsigned)u) << 16; return v.f;
}
__device__ __forceinline__ void stor(float* C, size_t i, float v) { C[i] = v; }
__device__ __forceinline__ void stor(u16* C, size_t i, float v) { C[i] = f2bf(v); }

__device__ __forceinline__ unsigned cvtpk(float a, float b) {
  unsigned r;
  asm("v_cvt_pk_bf16_f32 %0, %1, %2" : "=v"(r) : "v"(a), "v"(b));
  return r;
}
// swap: a.hi-lanes <-> b.lo-lanes. Operands MUST be distinct values
// (same-value copies may share a register -> self-swap corruption, R17 bug).
__device__ __forceinline__ void plswap(unsigned &a, unsigned &b) {
  asm volatile("v_permlane32_swap_b32 %0, %1" : "+v"(a), "+v"(b));
}

// ---------------------------------------------------------------------------
// Fused f32 -> bf16 conversion of TWO arrays in one launch.
// Blocks [0, nblkA) convert a -> da; the rest convert b -> db. 4 elems/thr.
// ---------------------------------------------------------------------------
__global__ void conv2_f32_bf16(const float* __restrict__ a, u16* __restrict__ da,
                               int nblkA, const float* __restrict__ b,
                               u16* __restrict__ db) {
  int blk = blockIdx.x;
  const float* src;
  u16* dst;
  int base;
  if (blk < nblkA) { src = a; dst = da; base = blk; }
  else             { src = b; dst = db; base = blk - nblkA; }
  int i = (base * 256 + threadIdx.x) * 4;
  f32x4 v = *(const f32x4*)(src + i);
  u16x4 o;
#pragma unroll
  for (int j = 0; j < 4; ++j) o[j] = f2bf(v[j]);
  *(u16x4*)(dst + i) = o;
}

__global__ void conv_f32_bf16(const float* __restrict__ src, u16* __restrict__ dst) {
  int i = (blockIdx.x * blockDim.x + threadIdx.x) * 4;
  f32x4 v = *(const f32x4*)(src + i);
  u16x4 o;
#pragma unroll
  for (int j = 0; j < 4; ++j) o[j] = f2bf(v[j]);
  *(u16x4*)(dst + i) = o;
}

// ---------------------------------------------------------------------------
// Pipelined 128x128 GEMM (T3/T4 schedule): BK=64, 4 waves (2x2), dbuf 64KB
// LDS -> 2 blocks/CU, depth-2 prefetch, counted vmcnt(8), both-sides XOR
// swizzle. Grid: (M/128)*(N/128), divisible by 8 (bijective XCD swizzle).
// TOUT: u16 (bf16 store) or float.
// ---------------------------------------------------------------------------
template <typename TOUT>
__global__ __launch_bounds__(256, 1)
void gemm128p_bt(const u16* __restrict__ A, const u16* __restrict__ B,
                 TOUT* __restrict__ C, int M, int N, int K) {
  __shared__ __align__(16) char smem[65536];    // 2 slots x (A 16KB + B 16KB)
  const int tid  = threadIdx.x;
  const int lane = tid & 63;
  const int wid  = tid >> 6;        // 0..3
  const int wr = wid >> 1, wc = wid & 1;
  const int fr = lane & 15, fq = lane >> 4;

  const int nwg = gridDim.x;
  const int wg  = (blockIdx.x & 7) * (nwg >> 3) + (blockIdx.x >> 3);
  const int nrt = M >> 7;
  const int rt  = wg % nrt, ct = wg / nrt;
  const int row0 = rt * 128, col0 = ct * 128;
  const int nt = K >> 6;

#define STAGE128(base, kt)                                                      \
  {                                                                             \
    _Pragma("unroll")                                                           \
    for (int j = 0; j < 4; ++j) {                                               \
      int c   = tid + j * 256;                                                  \
      int row = c >> 3;                                                         \
      int ke  = (((c & 7) ^ (row & 7)) * 8);                                    \
      const u16* sA = A + (size_t)(row0 + row) * K + (kt) * 64 + ke;            \
      __builtin_amdgcn_global_load_lds(                                         \
          (const __attribute__((address_space(1))) void*)sA,                    \
          (__attribute__((address_space(3))) void*)((base) + c * 16), 16, 0, 0);\
      const u16* sB = B + (size_t)(col0 + row) * K + (kt) * 64 + ke;            \
      __builtin_amdgcn_global_load_lds(                                         \
          (const __attribute__((address_space(1))) void*)sB,                    \
          (__attribute__((address_space(3))) void*)((base) + 16384 + c * 16), 16, 0, 0);\
    }                                                                           \
  }

  STAGE128(smem, 0);
  STAGE128(smem + 32768, 1);
  asm volatile("s_waitcnt vmcnt(8)" ::: "memory");   // tile 0 landed
  __builtin_amdgcn_s_barrier();
  __builtin_amdgcn_sched_barrier(0);

  f32x4 acc[4][4] = {};

  for (int t = 0; t < nt; ++t) {
    char* slot = smem + (t & 1) * 32768;

    bf16x8 af[4][2], bf[4][2];
#pragma unroll
    for (int mf = 0; mf < 4; ++mf)
#pragma unroll
      for (int kk = 0; kk < 2; ++kk) {
        int row = wr * 64 + mf * 16 + fr;
        int off = row * 128 + ((kk * 64 + fq * 16) ^ ((row & 7) << 4));
        af[mf][kk] = *(const bf16x8*)(slot + off);
      }
#pragma unroll
    for (int nf = 0; nf < 4; ++nf)
#pragma unroll
      for (int kk = 0; kk < 2; ++kk) {
        int row = wc * 64 + nf * 16 + fr;
        int off = row * 128 + ((kk * 64 + fq * 16) ^ ((row & 7) << 4));
        bf[nf][kk] = *(const bf16x8*)(slot + 16384 + off);
      }
    asm volatile("s_waitcnt lgkmcnt(0)" ::: "memory");
    __builtin_amdgcn_sched_barrier(0);
    __builtin_amdgcn_s_barrier();
    __builtin_amdgcn_sched_barrier(0);

    if (t + 2 < nt) STAGE128(slot, t + 2);
    __builtin_amdgcn_sched_barrier(0);

    __builtin_amdgcn_s_setprio(1);
#pragma unroll
    for (int kk = 0; kk < 2; ++kk)
#pragma unroll
      for (int mf = 0; mf < 4; ++mf)
#pragma unroll
        for (int nf = 0; nf < 4; ++nf)
          acc[mf][nf] = __builtin_amdgcn_mfma_f32_16x16x32_bf16(
              af[mf][kk], bf[nf][kk], acc[mf][nf], 0, 0, 0);
    __builtin_amdgcn_s_setprio(0);

    if (t + 2 < nt) {
      asm volatile("s_waitcnt vmcnt(8)" ::: "memory");
    } else {
      asm volatile("s_waitcnt vmcnt(0)" ::: "memory");
    }
    __builtin_amdgcn_s_barrier();
    __builtin_amdgcn_sched_barrier(0);
  }
#undef STAGE128

#pragma unroll
  for (int mf = 0; mf < 4; ++mf)
#pragma unroll
    for (int nf = 0; nf < 4; ++nf) {
      int row = row0 + wr * 64 + mf * 16 + fq * 4;
      int col = col0 + wc * 64 + nf * 16 + fr;
#pragma unroll
      for (int r = 0; r < 4; ++r)
        stor(C, (size_t)(row + r) * N + col, acc[mf][nf][r]);
    }
}

// ---------------------------------------------------------------------------
// RoPE in-place on q,k parts of qkv. Q pre-scaled by QSCALE.
// ---------------------------------------------------------------------------
__global__ void rope_qk(u16* qkv) {
  int idx = blockIdx.x * blockDim.x + threadIdx.x;
  int i4 = idx & 15;
  int h  = (idx >> 4) & 15;
  int t  = (idx >> 8) & 1;
  int s  = idx >> 9;
  u16* p = qkv + (size_t)s * 6144 + t * 2048 + h * 128 + i4 * 8;
  const float post = t ? 1.0f : QSCALE;
  u16x8 v = *(const u16x8*)p;
  u16x8 w;
#pragma unroll
  for (int j = 0; j < 4; ++j) {
    int i = i4 * 4 + j;
    float inv = exp2f(-(float)i * 0.2076205059304601f);  // 10000^(-i/64)
    float ang = (float)s * inv;
    float sn, cs;
    sincosf(ang, &sn, &cs);
    float e = bf2f(v[2 * j]);
    float o = bf2f(v[2 * j + 1]);
    w[2 * j]     = f2bf((e * cs - o * sn) * post);
    w[2 * j + 1] = f2bf((e * sn + o * cs) * post);
  }
  *(u16x8*)p = w;
}

// ---------------------------------------------------------------------------
// Fused repack of V and K into per-(head, kv-tile) 8KB tiles, one launch.
// Grid (64, 80): y < 64 -> V path (slot-permuted transpose);
//                y >= 64 -> K path (h = y - 64, t = x).
// ---------------------------------------------------------------------------
__global__ void repack_kv(const u16* __restrict__ qkv, u16* __restrict__ vt2,
                          u16* __restrict__ kt2) {
  if (blockIdx.y < 64) {
    // ---- V path ----
    __shared__ u16 tile[32][33];
    int s0 = blockIdx.x * 32, c0 = blockIdx.y * 32;
    int tx = threadIdx.x & 31, ty = threadIdx.x >> 5;  // 32 x 8
#pragma unroll
    for (int i = ty; i < 32; i += 8)
      tile[i][tx] = qkv[(size_t)(s0 + i) * 6144 + 4096 + c0 + tx];
    __syncthreads();
    int t = s0 >> 5;
#pragma unroll
    for (int i = ty; i < 32; i += 8) {
      int col = c0 + i;                 // h*128 + d
      int h = col >> 7, d = col & 127;
      int slot = ((d >> 3) << 5) + ((tx >> 3) << 3) + (d & 7);
      vt2[((size_t)(h * 64 + t)) * 4096 + slot * 8 + (tx & 7)] = tile[tx][i];
    }
  } else {
    // ---- K path ----
    int t = blockIdx.x, h = blockIdx.y - 64;
    int j = threadIdx.x >> 3;        // kv row 0..31
    int c = threadIdx.x & 7;         // d-chunk of 16 u16
    const u16* src = qkv + (size_t)(t * 32 + j) * 6144 + 2048 + h * 128 + c * 16;
    u16* dst = kt2 + ((size_t)(h * 64 + t)) * 4096 + c * 512 + j * 16;
    *(u16x8*)dst       = *(const u16x8*)src;
    *(u16x8*)(dst + 8) = *(const u16x8*)(src + 8);
  }
}

// ---------------------------------------------------------------------------
// Causal flash attention: 4-wave FLAT blocks, all-direct K/V, LPT order.
// __launch_bounds__(256, 2): best-measured config (VGPR 96, no spill, 73us).
// R28's unroll x2 raised VGPR to 160 -> occupancy 11% -> 114us: reverted.
// ---------------------------------------------------------------------------
__global__ __launch_bounds__(256, 2)
void attn_fwd(const u16* __restrict__ qkv, const u16* __restrict__ kt2,
              const u16* __restrict__ vt2, u16* __restrict__ ao) {
  const int f    = blockIdx.y * 64 + blockIdx.x;
  const int h    = ((f & 7) << 1) | ((f >> 3) & 1);  // 2 heads per XCD
  const int tile = 63 - (f >> 4);                     // LPT: longest first
  const int tid  = threadIdx.x;
  const int lane = tid & 63;
  const int wid  = tid >> 6;        // 0..3 = kv-split slot
  const int l31  = lane & 31;
  const int hh   = lane >> 5;
  const int q0 = tile * 32;

  __shared__ __align__(16) char smem[17408];
  char* bufQ = smem;                                       // 8KB, loop phase
  float (*Obuf)[128] = (float(*)[128])smem;                // overlay post-loop (16KB)
  float (*mls)[32][2] = (float(*)[32][2])(smem + 16384);   // overlay post-loop (1KB)

  const char* qkvB = (const char*)qkv;
  const char* ktH = (const char*)kt2 + (size_t)h * 64 * 8192;
  const char* vtH = (const char*)vt2 + (size_t)h * 64 * 8192;

  // ---- prologue: stage shared Q (2 instrs/wave) ----
#pragma unroll
  for (int kk = 0; kk < 2; ++kk) {
    int k = wid * 2 + kk;
    int s = k * 64 + lane;
    int row = ((s >> 7) << 3) | (s & 7);
    int c = (s >> 3) & 15;
    const char* src = qkvB + (size_t)(q0 + row) * 12288 + h * 256 + c * 16;
    __builtin_amdgcn_global_load_lds(
        (const __attribute__((address_space(1))) void*)src,
        (__attribute__((address_space(3))) void*)(bufQ + k * 1024 + lane * 16), 16, 0, 0);
  }
  __syncthreads();   // Q ready

  f32x16 oacc[4] = {};              // q=(r&3)+8*(r>>2)+4*hh, d=32c+l31
  float M = -1e30f, L = 0.f;

  const int qkBase = ((l31 >> 3) << 11) + (hh << 7) + ((l31 & 7) << 4);  // Q: + s*256
  const int vBase  = ((l31 >> 3) << 9)  + (hh << 7) + ((l31 & 7) << 4);  // V: + c*2048 + tt*256
  const int kBase  = l31 * 32 + hh * 16;                                  // K: + s*1024

  for (int t = wid; t <= tile; t += 4) {
    const char* kt = ktH + (size_t)t * 8192;
    const char* vt = vtH + (size_t)t * 8192;

    // V fragments early (consumed at PV -> latency hidden by design)
    bf16x8 vf[4][2];
#pragma unroll
    for (int c = 0; c < 4; ++c)
#pragma unroll
      for (int tt = 0; tt < 2; ++tt)
        vf[c][tt] = *(const bf16x8*)(vt + vBase + c * 2048 + tt * 256);

    // QK^T swapped: A = K rows (direct), B = Q rows (LDS); S[kv][q], q = l31
    f32x16 sc = {};
    {
      bf16x8 ka[4], qa[4];
#pragma unroll
      for (int s = 0; s < 4; ++s) {
        ka[s] = *(const bf16x8*)(kt + kBase + s * 1024);
        qa[s] = *(const bf16x8*)(bufQ + qkBase + s * 256);
      }
      __builtin_amdgcn_s_setprio(1);
#pragma unroll
      for (int s = 0; s < 4; ++s)
        sc = __builtin_amdgcn_mfma_f32_32x32x16_bf16(ka[s], qa[s], sc, 0, 0, 0);
      __builtin_amdgcn_s_setprio(0);
#pragma unroll
      for (int s = 0; s < 4; ++s) {
        ka[s] = *(const bf16x8*)(kt + kBase + (s + 4) * 1024);
        qa[s] = *(const bf16x8*)(bufQ + qkBase + (s + 4) * 256);
      }
      __builtin_amdgcn_s_setprio(1);
#pragma unroll
      for (int s = 0; s < 4; ++s)
        sc = __builtin_amdgcn_mfma_f32_32x32x16_bf16(ka[s], qa[s], sc, 0, 0, 0);
      __builtin_amdgcn_s_setprio(0);
    }

    // causal mask on the diagonal tile
    if (t == tile) {
#pragma unroll
      for (int r = 0; r < 16; ++r) {
        int kv = (r & 3) + 8 * (r >> 2) + 4 * hh;
        if (kv > l31) sc[r] = -1e30f;
      }
    }

    // per-lane online softmax, T13 defer-max
    float pm = fmaxf(fmaxf(fmaxf(sc[0], sc[1]), fmaxf(sc[2], sc[3])),
                     fmaxf(fmaxf(sc[4], sc[5]), fmaxf(sc[6], sc[7])));
    float pm2 = fmaxf(fmaxf(fmaxf(sc[8], sc[9]), fmaxf(sc[10], sc[11])),
                      fmaxf(fmaxf(sc[12], sc[13]), fmaxf(sc[14], sc[15])));
    pm = fmaxf(pm, pm2);
    pm = fmaxf(pm, __shfl_xor(pm, 32, 64));

    bool defer = (pm <= M + 8.0f);
    if (!__all(defer)) {
      float Mn = fmaxf(M, pm);
      float corr = exp2f(M - Mn);
      M = Mn;
      L *= corr;
#pragma unroll
      for (int r = 0; r < 16; ++r) {
        float cr = __shfl(corr, (r & 3) + 8 * (r >> 2) + 4 * hh, 64);
#pragma unroll
        for (int c = 0; c < 4; ++c) oacc[c][r] *= cr;
      }
    }

#pragma unroll
    for (int r = 0; r < 16; ++r) sc[r] = exp2f(sc[r] - M);
    float rs = ((sc[0] + sc[1]) + (sc[2] + sc[3])) + ((sc[4] + sc[5]) + (sc[6] + sc[7]))
             + ((sc[8] + sc[9]) + (sc[10] + sc[11])) + ((sc[12] + sc[13]) + (sc[14] + sc[15]));
    rs += __shfl_xor(rs, 32, 64);
    L += rs;

    // pack P into PV A-frags and accumulate O
#pragma unroll
    for (int tt = 0; tt < 2; ++tt) {
      unsigned A0 = cvtpk(sc[8 * tt + 0], sc[8 * tt + 1]);
      unsigned A1 = cvtpk(sc[8 * tt + 2], sc[8 * tt + 3]);
      unsigned B0 = cvtpk(sc[8 * tt + 4], sc[8 * tt + 5]);
      unsigned B1 = cvtpk(sc[8 * tt + 6], sc[8 * tt + 7]);
      plswap(A0, B0);
      plswap(A1, B1);
      union { unsigned w[4]; bf16x8 v; } pa;
      pa.w[0] = A0; pa.w[1] = A1; pa.w[2] = B0; pa.w[3] = B1;
      __builtin_amdgcn_s_setprio(1);
#pragma unroll
      for (int c = 0; c < 4; ++c)
        oacc[c] = __builtin_amdgcn_mfma_f32_32x32x16_bf16(pa.v, vf[c][tt], oacc[c], 0, 0, 0);
      __builtin_amdgcn_s_setprio(0);
    }
  }

  // ---- overlay handoff: loop done -> Q buffer dead ----
  __syncthreads();
  if (hh == 0) { mls[wid][l31][0] = M; mls[wid][l31][1] = L; }
  __syncthreads();

  // flash merge over the 4 kv-split partials
  for (int w = 0; w < 4; ++w) {
    if (wid == w) {
#pragma unroll
      for (int r = 0; r < 16; ++r) {
        int q = (r & 3) + 8 * (r >> 2) + 4 * hh;
        float m_own = mls[wid][q][0];   // per-row max from LDS (R20 fix)
        float Mg = fmaxf(fmaxf(mls[0][q][0], mls[1][q][0]),
                         fmaxf(mls[2][q][0], mls[3][q][0]));
        float s = exp2f(m_own - Mg);
#pragma unroll
        for (int c = 0; c < 4; ++c) {
          float v = oacc[c][r] * s;
          if (w == 0) Obuf[q][32 * c + l31] = v;
          else        Obuf[q][32 * c + l31] += v;
        }
      }
    }
    __syncthreads();
  }

  // write-out: wave wid normalizes+stores rows wid*8 .. wid*8+7
#pragma unroll
  for (int rr = 0; rr < 8; ++rr) {
    int row = wid * 8 + rr;
    float Mg = fmaxf(fmaxf(mls[0][row][0], mls[1][row][0]),
                     fmaxf(mls[2][row][0], mls[3][row][0]));
    float lt = 0.f;
#pragma unroll
    for (int w2 = 0; w2 < 4; ++w2)
      lt += exp2f(mls[w2][row][0] - Mg) * mls[w2][row][1];
    float inv = 1.0f / lt;
    float v0 = Obuf[row][lane * 2]     * inv;
    float v1 = Obuf[row][lane * 2 + 1] * inv;
    unsigned pack = (unsigned)f2bf(v0) | ((unsigned)f2bf(v1) << 16);
    *(unsigned*)&ao[(size_t)(q0 + row) * 2048 + h * 128 + lane * 2] = pack;
  }
}

// ---------------------------------------------------------------------------
extern "C" void kernel_launch(void* const* d_in, const int* in_sizes, int n_in,
                              void* d_out, int out_size, void* d_ws, size_t ws_size,
                              hipStream_t stream) {
  const float* x     = (const float*)d_in[0];   // 2048 x 2048 f32
  const float* w_qkv = (const float*)d_in[1];   // 6144 x 2048 f32
  const float* w_out = (const float*)d_in[2];   // 2048 x 2048 f32
  float* out = (float*)d_out;                   // 2048 x 2048 f32
  const int S = 2048, H = 2048, O3 = 6144;

  // workspace (u16 elems), peak 58.8 MB with aliasing:
  u16* qkv     = (u16*)d_ws;                    // S*O3 = 25.2 MB
  u16* x_bf    = qkv + (size_t)S * O3;          //  8.4 MB
  u16* wqkv_bf = x_bf + (size_t)S * H;          // 25.2 MB region
  u16* ao      = x_bf;                          // alias (x_bf dead after GEMM1)
  u16* vt2     = wqkv_bf;                       // alias: 8.4 MB
  u16* kt2     = wqkv_bf + (size_t)H * S;       // alias: 8.4 MB
  u16* wout_bf = wqkv_bf + 2 * (size_t)H * S;   // alias: 8.4 MB (= 25.2 total)

  // 1. convert x and w_qkv to bf16 (single fused launch)
  conv2_f32_bf16<<<(S * H) / 1024 + (O3 * H) / 1024, 256, 0, stream>>>(
      x, x_bf, (S * H) / 1024, w_qkv, wqkv_bf);
  // 2. qkv = x @ w_qkv^T  (M=2048, N=6144, K=2048) -- pipelined 128^2, 768 blocks
  gemm128p_bt<u16><<<(S / 128) * (O3 / 128), 256, 0, stream>>>(x_bf, wqkv_bf, qkv, S, O3, H);
  // 3. RoPE on q,k in place (q pre-scaled by QSCALE)
  rope_qk<<<(S * 2 * 16 * 16) / 256, 256, 0, stream>>>(qkv);
  // 4. repack V and K into per-(h,t) tiles (single fused launch)
  repack_kv<<<dim3(64, 80), 256, 0, stream>>>(qkv, vt2, kt2);
  // 5. convert w_out (into region freed after GEMM1)
  conv_f32_bf16<<<(S * H) / 1024, 256, 0, stream>>>(w_out, wout_bf);
  // 6. causal flash attention (4-wave flat blocks, LPT order) -> ao
  attn_fwd<<<dim3(64, 16), 256, 0, stream>>>(qkv, kt2, vt2, ao);
  // 7. out = ao @ w_out^T  (M=2048, N=2048, K=2048) -- pipelined 128^2, f32 out
  gemm128p_bt<float><<<(S / 128) * (H / 128), 256, 0, stream>>>(ao, wout_bf, out, S, H, H);
}

// Round 30
// 164.721 us; speedup vs baseline: 1.1880x; 1.0145x over previous
//
#include <hip/hip_runtime.h>
#include <math.h>

typedef unsigned short u16;
typedef __attribute__((ext_vector_type(4))) float f32x4;
typedef __attribute__((ext_vector_type(16))) float f32x16;
typedef __attribute__((ext_vector_type(4))) unsigned short u16x4;
typedef __attribute__((ext_vector_type(8))) short bf16x8;
typedef __attribute__((ext_vector_type(8))) unsigned short u16x8;

#define LOG2E 1.4426950408889634f
#define QSCALE (0.08838834764831845f * LOG2E)   // 1/sqrt(128) * log2(e)

__device__ __forceinline__ u16 f2bf(float f) {
  union { float f; unsigned u; } v; v.f = f;
  unsigned r = (v.u + 0x7fff + ((v.u >> 16) & 1)) >> 16;
  return (u16)r;
}
__device__ __forceinline__ float bf2f(u16 u) {
  union { unsigned u; float f; } v; v.u = ((unsigned)u) << 16; return v.f;
}
__device__ __forceinline__ void stor(float* C, size_t i, float v) { C[i] = v; }
__device__ __forceinline__ void stor(u16* C, size_t i, float v) { C[i] = f2bf(v); }

__device__ __forceinline__ unsigned cvtpk(float a, float b) {
  unsigned r;
  asm("v_cvt_pk_bf16_f32 %0, %1, %2" : "=v"(r) : "v"(a), "v"(b));
  return r;
}
// swap: a.hi-lanes <-> b.lo-lanes. Operands MUST be distinct values
// (same-value copies may share a register -> self-swap corruption, R17 bug).
__device__ __forceinline__ void plswap(unsigned &a, unsigned &b) {
  asm volatile("v_permlane32_swap_b32 %0, %1" : "+v"(a), "+v"(b));
}

// ---------------------------------------------------------------------------
// Fused f32 -> bf16 conversion of TWO arrays in one launch.
// ---------------------------------------------------------------------------
__global__ void conv2_f32_bf16(const float* __restrict__ a, u16* __restrict__ da,
                               int nblkA, const float* __restrict__ b,
                               u16* __restrict__ db) {
  int blk = blockIdx.x;
  const float* src;
  u16* dst;
  int base;
  if (blk < nblkA) { src = a; dst = da; base = blk; }
  else             { src = b; dst = db; base = blk - nblkA; }
  int i = (base * 256 + threadIdx.x) * 4;
  f32x4 v = *(const f32x4*)(src + i);
  u16x4 o;
#pragma unroll
  for (int j = 0; j < 4; ++j) o[j] = f2bf(v[j]);
  *(u16x4*)(dst + i) = o;
}

__global__ void conv_f32_bf16(const float* __restrict__ src, u16* __restrict__ dst) {
  int i = (blockIdx.x * blockDim.x + threadIdx.x) * 4;
  f32x4 v = *(const f32x4*)(src + i);
  u16x4 o;
#pragma unroll
  for (int j = 0; j < 4; ++j) o[j] = f2bf(v[j]);
  *(u16x4*)(dst + i) = o;
}

// ---------------------------------------------------------------------------
// Pipelined 128x128 GEMM (T3/T4 schedule): BK=64, 4 waves (2x2), dbuf 64KB
// LDS, depth-2 prefetch, counted vmcnt(8), both-sides XOR swizzle. (proven)
// ---------------------------------------------------------------------------
template <typename TOUT>
__global__ __launch_bounds__(256, 1)
void gemm128p_bt(const u16* __restrict__ A, const u16* __restrict__ B,
                 TOUT* __restrict__ C, int M, int N, int K) {
  __shared__ __align__(16) char smem[65536];    // 2 slots x (A 16KB + B 16KB)
  const int tid  = threadIdx.x;
  const int lane = tid & 63;
  const int wid  = tid >> 6;        // 0..3
  const int wr = wid >> 1, wc = wid & 1;
  const int fr = lane & 15, fq = lane >> 4;

  const int nwg = gridDim.x;
  const int wg  = (blockIdx.x & 7) * (nwg >> 3) + (blockIdx.x >> 3);
  const int nrt = M >> 7;
  const int rt  = wg % nrt, ct = wg / nrt;
  const int row0 = rt * 128, col0 = ct * 128;
  const int nt = K >> 6;

#define STAGE128(base, kt)                                                      \
  {                                                                             \
    _Pragma("unroll")                                                           \
    for (int j = 0; j < 4; ++j) {                                               \
      int c   = tid + j * 256;                                                  \
      int row = c >> 3;                                                         \
      int ke  = (((c & 7) ^ (row & 7)) * 8);                                    \
      const u16* sA = A + (size_t)(row0 + row) * K + (kt) * 64 + ke;            \
      __builtin_amdgcn_global_load_lds(                                         \
          (const __attribute__((address_space(1))) void*)sA,                    \
          (__attribute__((address_space(3))) void*)((base) + c * 16), 16, 0, 0);\
      const u16* sB = B + (size_t)(col0 + row) * K + (kt) * 64 + ke;            \
      __builtin_amdgcn_global_load_lds(                                         \
          (const __attribute__((address_space(1))) void*)sB,                    \
          (__attribute__((address_space(3))) void*)((base) + 16384 + c * 16), 16, 0, 0);\
    }                                                                           \
  }

  STAGE128(smem, 0);
  STAGE128(smem + 32768, 1);
  asm volatile("s_waitcnt vmcnt(8)" ::: "memory");   // tile 0 landed
  __builtin_amdgcn_s_barrier();
  __builtin_amdgcn_sched_barrier(0);

  f32x4 acc[4][4] = {};

  for (int t = 0; t < nt; ++t) {
    char* slot = smem + (t & 1) * 32768;

    bf16x8 af[4][2], bf[4][2];
#pragma unroll
    for (int mf = 0; mf < 4; ++mf)
#pragma unroll
      for (int kk = 0; kk < 2; ++kk) {
        int row = wr * 64 + mf * 16 + fr;
        int off = row * 128 + ((kk * 64 + fq * 16) ^ ((row & 7) << 4));
        af[mf][kk] = *(const bf16x8*)(slot + off);
      }
#pragma unroll
    for (int nf = 0; nf < 4; ++nf)
#pragma unroll
      for (int kk = 0; kk < 2; ++kk) {
        int row = wc * 64 + nf * 16 + fr;
        int off = row * 128 + ((kk * 64 + fq * 16) ^ ((row & 7) << 4));
        bf[nf][kk] = *(const bf16x8*)(slot + 16384 + off);
      }
    asm volatile("s_waitcnt lgkmcnt(0)" ::: "memory");
    __builtin_amdgcn_sched_barrier(0);
    __builtin_amdgcn_s_barrier();
    __builtin_amdgcn_sched_barrier(0);

    if (t + 2 < nt) STAGE128(slot, t + 2);
    __builtin_amdgcn_sched_barrier(0);

    __builtin_amdgcn_s_setprio(1);
#pragma unroll
    for (int kk = 0; kk < 2; ++kk)
#pragma unroll
      for (int mf = 0; mf < 4; ++mf)
#pragma unroll
        for (int nf = 0; nf < 4; ++nf)
          acc[mf][nf] = __builtin_amdgcn_mfma_f32_16x16x32_bf16(
              af[mf][kk], bf[nf][kk], acc[mf][nf], 0, 0, 0);
    __builtin_amdgcn_s_setprio(0);

    if (t + 2 < nt) {
      asm volatile("s_waitcnt vmcnt(8)" ::: "memory");
    } else {
      asm volatile("s_waitcnt vmcnt(0)" ::: "memory");
    }
    __builtin_amdgcn_s_barrier();
    __builtin_amdgcn_sched_barrier(0);
  }
#undef STAGE128

#pragma unroll
  for (int mf = 0; mf < 4; ++mf)
#pragma unroll
    for (int nf = 0; nf < 4; ++nf) {
      int row = row0 + wr * 64 + mf * 16 + fq * 4;
      int col = col0 + wc * 64 + nf * 16 + fr;
#pragma unroll
      for (int r = 0; r < 4; ++r)
        stor(C, (size_t)(row + r) * N + col, acc[mf][nf][r]);
    }
}

// ---------------------------------------------------------------------------
// Pipelined 128x64 GEMM (same T3/T4 schedule, parameter-shrunk): BK=64,
// 4 waves (2Mx2N, 64x32/wave), dbuf 48KB LDS -> up to 3 blocks/CU, depth-2
// prefetch, counted vmcnt(6) (6 stage-instrs/tile). For GEMM2: grid
// 16x32 = 512 blocks = 2/CU exactly (vs 128^2's 256 = 1/CU).
// ---------------------------------------------------------------------------
template <typename TOUT>
__global__ __launch_bounds__(256, 1)
void gemm128x64p_bt(const u16* __restrict__ A, const u16* __restrict__ B,
                    TOUT* __restrict__ C, int M, int N, int K) {
  __shared__ __align__(16) char smem[49152];    // 2 slots x (A 16KB + B 8KB)
  const int tid  = threadIdx.x;
  const int lane = tid & 63;
  const int wid  = tid >> 6;        // 0..3
  const int wr = wid >> 1, wc = wid & 1;
  const int fr = lane & 15, fq = lane >> 4;

  const int nwg = gridDim.x;
  const int wg  = (blockIdx.x & 7) * (nwg >> 3) + (blockIdx.x >> 3);
  const int nrt = M >> 7;
  const int rt  = wg % nrt, ct = wg / nrt;
  const int row0 = rt * 128, col0 = ct * 64;
  const int nt = K >> 6;

#define STAGE12864(base, kt)                                                    \
  {                                                                             \
    _Pragma("unroll")                                                           \
    for (int j = 0; j < 4; ++j) {      /* A: 128 rows x 64 k = 16KB */          \
      int c   = tid + j * 256;                                                  \
      int row = c >> 3;                                                         \
      int ke  = (((c & 7) ^ (row & 7)) * 8);                                    \
      const u16* sA = A + (size_t)(row0 + row) * K + (kt) * 64 + ke;            \
      __builtin_amdgcn_global_load_lds(                                         \
          (const __attribute__((address_space(1))) void*)sA,                    \
          (__attribute__((address_space(3))) void*)((base) + c * 16), 16, 0, 0);\
    }                                                                           \
    _Pragma("unroll")                                                           \
    for (int j = 0; j < 2; ++j) {      /* B: 64 rows x 64 k = 8KB */            \
      int c   = tid + j * 256;                                                  \
      int row = c >> 3;                                                         \
      int ke  = (((c & 7) ^ (row & 7)) * 8);                                    \
      const u16* sB = B + (size_t)(col0 + row) * K + (kt) * 64 + ke;            \
      __builtin_amdgcn_global_load_lds(                                         \
          (const __attribute__((address_space(1))) void*)sB,                    \
          (__attribute__((address_space(3))) void*)((base) + 16384 + c * 16), 16, 0, 0);\
    }                                                                           \
  }

  STAGE12864(smem, 0);
  STAGE12864(smem + 24576, 1);
  asm volatile("s_waitcnt vmcnt(6)" ::: "memory");   // tile 0 landed
  __builtin_amdgcn_s_barrier();
  __builtin_amdgcn_sched_barrier(0);

  f32x4 acc[4][2] = {};

  for (int t = 0; t < nt; ++t) {
    char* slot = smem + (t & 1) * 24576;

    bf16x8 af[4][2], bf[2][2];
#pragma unroll
    for (int mf = 0; mf < 4; ++mf)
#pragma unroll
      for (int kk = 0; kk < 2; ++kk) {
        int row = wr * 64 + mf * 16 + fr;
        int off = row * 128 + ((kk * 64 + fq * 16) ^ ((row & 7) << 4));
        af[mf][kk] = *(const bf16x8*)(slot + off);
      }
#pragma unroll
    for (int nf = 0; nf < 2; ++nf)
#pragma unroll
      for (int kk = 0; kk < 2; ++kk) {
        int row = wc * 32 + nf * 16 + fr;
        int off = row * 128 + ((kk * 64 + fq * 16) ^ ((row & 7) << 4));
        bf[nf][kk] = *(const bf16x8*)(slot + 16384 + off);
      }
    asm volatile("s_waitcnt lgkmcnt(0)" ::: "memory");
    __builtin_amdgcn_sched_barrier(0);
    __builtin_amdgcn_s_barrier();
    __builtin_amdgcn_sched_barrier(0);

    if (t + 2 < nt) STAGE12864(slot, t + 2);
    __builtin_amdgcn_sched_barrier(0);

    __builtin_amdgcn_s_setprio(1);
#pragma unroll
    for (int kk = 0; kk < 2; ++kk)
#pragma unroll
      for (int mf = 0; mf < 4; ++mf)
#pragma unroll
        for (int nf = 0; nf < 2; ++nf)
          acc[mf][nf] = __builtin_amdgcn_mfma_f32_16x16x32_bf16(
              af[mf][kk], bf[nf][kk], acc[mf][nf], 0, 0, 0);
    __builtin_amdgcn_s_setprio(0);

    if (t + 2 < nt) {
      asm volatile("s_waitcnt vmcnt(6)" ::: "memory");
    } else {
      asm volatile("s_waitcnt vmcnt(0)" ::: "memory");
    }
    __builtin_amdgcn_s_barrier();
    __builtin_amdgcn_sched_barrier(0);
  }
#undef STAGE12864

#pragma unroll
  for (int mf = 0; mf < 4; ++mf)
#pragma unroll
    for (int nf = 0; nf < 2; ++nf) {
      int row = row0 + wr * 64 + mf * 16 + fq * 4;
      int col = col0 + wc * 32 + nf * 16 + fr;
#pragma unroll
      for (int r = 0; r < 4; ++r)
        stor(C, (size_t)(row + r) * N + col, acc[mf][nf][r]);
    }
}

// ---------------------------------------------------------------------------
// RoPE in-place on q,k parts of qkv. Q pre-scaled by QSCALE.
// ---------------------------------------------------------------------------
__global__ void rope_qk(u16* qkv) {
  int idx = blockIdx.x * blockDim.x + threadIdx.x;
  int i4 = idx & 15;
  int h  = (idx >> 4) & 15;
  int t  = (idx >> 8) & 1;
  int s  = idx >> 9;
  u16* p = qkv + (size_t)s * 6144 + t * 2048 + h * 128 + i4 * 8;
  const float post = t ? 1.0f : QSCALE;
  u16x8 v = *(const u16x8*)p;
  u16x8 w;
#pragma unroll
  for (int j = 0; j < 4; ++j) {
    int i = i4 * 4 + j;
    float inv = exp2f(-(float)i * 0.2076205059304601f);  // 10000^(-i/64)
    float ang = (float)s * inv;
    float sn, cs;
    sincosf(ang, &sn, &cs);
    float e = bf2f(v[2 * j]);
    float o = bf2f(v[2 * j + 1]);
    w[2 * j]     = f2bf((e * cs - o * sn) * post);
    w[2 * j + 1] = f2bf((e * sn + o * cs) * post);
  }
  *(u16x8*)p = w;
}

// ---------------------------------------------------------------------------
// Fused repack of V and K into per-(head, kv-tile) 8KB tiles, one launch.
// ---------------------------------------------------------------------------
__global__ void repack_kv(const u16* __restrict__ qkv, u16* __restrict__ vt2,
                          u16* __restrict__ kt2) {
  if (blockIdx.y < 64) {
    __shared__ u16 tile[32][33];
    int s0 = blockIdx.x * 32, c0 = blockIdx.y * 32;
    int tx = threadIdx.x & 31, ty = threadIdx.x >> 5;  // 32 x 8
#pragma unroll
    for (int i = ty; i < 32; i += 8)
      tile[i][tx] = qkv[(size_t)(s0 + i) * 6144 + 4096 + c0 + tx];
    __syncthreads();
    int t = s0 >> 5;
#pragma unroll
    for (int i = ty; i < 32; i += 8) {
      int col = c0 + i;                 // h*128 + d
      int h = col >> 7, d = col & 127;
      int slot = ((d >> 3) << 5) + ((tx >> 3) << 3) + (d & 7);
      vt2[((size_t)(h * 64 + t)) * 4096 + slot * 8 + (tx & 7)] = tile[tx][i];
    }
  } else {
    int t = blockIdx.x, h = blockIdx.y - 64;
    int j = threadIdx.x >> 3;        // kv row 0..31
    int c = threadIdx.x & 7;         // d-chunk of 16 u16
    const u16* src = qkv + (size_t)(t * 32 + j) * 6144 + 2048 + h * 128 + c * 16;
    u16* dst = kt2 + ((size_t)(h * 64 + t)) * 4096 + c * 512 + j * 16;
    *(u16x8*)dst       = *(const u16x8*)src;
    *(u16x8*)(dst + 8) = *(const u16x8*)(src + 8);
  }
}

// ---------------------------------------------------------------------------
// Causal flash attention: 4-wave FLAT blocks, all-direct K/V, LPT order.
// __launch_bounds__(256, 2): best-measured config (VGPR 96, 73us).
// ---------------------------------------------------------------------------
__global__ __launch_bounds__(256, 2)
void attn_fwd(const u16* __restrict__ qkv, const u16* __restrict__ kt2,
              const u16* __restrict__ vt2, u16* __restrict__ ao) {
  const int f    = blockIdx.y * 64 + blockIdx.x;
  const int h    = ((f & 7) << 1) | ((f >> 3) & 1);  // 2 heads per XCD
  const int tile = 63 - (f >> 4);                     // LPT: longest first
  const int tid  = threadIdx.x;
  const int lane = tid & 63;
  const int wid  = tid >> 6;        // 0..3 = kv-split slot
  const int l31  = lane & 31;
  const int hh   = lane >> 5;
  const int q0 = tile * 32;

  __shared__ __align__(16) char smem[17408];
  char* bufQ = smem;                                       // 8KB, loop phase
  float (*Obuf)[128] = (float(*)[128])smem;                // overlay post-loop (16KB)
  float (*mls)[32][2] = (float(*)[32][2])(smem + 16384);   // overlay post-loop (1KB)

  const char* qkvB = (const char*)qkv;
  const char* ktH = (const char*)kt2 + (size_t)h * 64 * 8192;
  const char* vtH = (const char*)vt2 + (size_t)h * 64 * 8192;

  // ---- prologue: stage shared Q (2 instrs/wave) ----
#pragma unroll
  for (int kk = 0; kk < 2; ++kk) {
    int k = wid * 2 + kk;
    int s = k * 64 + lane;
    int row = ((s >> 7) << 3) | (s & 7);
    int c = (s >> 3) & 15;
    const char* src = qkvB + (size_t)(q0 + row) * 12288 + h * 256 + c * 16;
    __builtin_amdgcn_global_load_lds(
        (const __attribute__((address_space(1))) void*)src,
        (__attribute__((address_space(3))) void*)(bufQ + k * 1024 + lane * 16), 16, 0, 0);
  }
  __syncthreads();   // Q ready

  f32x16 oacc[4] = {};              // q=(r&3)+8*(r>>2)+4*hh, d=32c+l31
  float M = -1e30f, L = 0.f;

  const int qkBase = ((l31 >> 3) << 11) + (hh << 7) + ((l31 & 7) << 4);  // Q: + s*256
  const int vBase  = ((l31 >> 3) << 9)  + (hh << 7) + ((l31 & 7) << 4);  // V: + c*2048 + tt*256
  const int kBase  = l31 * 32 + hh * 16;                                  // K: + s*1024

  for (int t = wid; t <= tile; t += 4) {
    const char* kt = ktH + (size_t)t * 8192;
    const char* vt = vtH + (size_t)t * 8192;

    // V fragments early (consumed at PV -> latency hidden by design)
    bf16x8 vf[4][2];
#pragma unroll
    for (int c = 0; c < 4; ++c)
#pragma unroll
      for (int tt = 0; tt < 2; ++tt)
        vf[c][tt] = *(const bf16x8*)(vt + vBase + c * 2048 + tt * 256);

    // QK^T swapped: A = K rows (direct), B = Q rows (LDS); S[kv][q], q = l31
    f32x16 sc = {};
    {
      bf16x8 ka[4], qa[4];
#pragma unroll
      for (int s = 0; s < 4; ++s) {
        ka[s] = *(const bf16x8*)(kt + kBase + s * 1024);
        qa[s] = *(const bf16x8*)(bufQ + qkBase + s * 256);
      }
      __builtin_amdgcn_s_setprio(1);
#pragma unroll
      for (int s = 0; s < 4; ++s)
        sc = __builtin_amdgcn_mfma_f32_32x32x16_bf16(ka[s], qa[s], sc, 0, 0, 0);
      __builtin_amdgcn_s_setprio(0);
#pragma unroll
      for (int s = 0; s < 4; ++s) {
        ka[s] = *(const bf16x8*)(kt + kBase + (s + 4) * 1024);
        qa[s] = *(const bf16x8*)(bufQ + qkBase + (s + 4) * 256);
      }
      __builtin_amdgcn_s_setprio(1);
#pragma unroll
      for (int s = 0; s < 4; ++s)
        sc = __builtin_amdgcn_mfma_f32_32x32x16_bf16(ka[s], qa[s], sc, 0, 0, 0);
      __builtin_amdgcn_s_setprio(0);
    }

    // causal mask on the diagonal tile
    if (t == tile) {
#pragma unroll
      for (int r = 0; r < 16; ++r) {
        int kv = (r & 3) + 8 * (r >> 2) + 4 * hh;
        if (kv > l31) sc[r] = -1e30f;
      }
    }

    // per-lane online softmax, T13 defer-max
    float pm = fmaxf(fmaxf(fmaxf(sc[0], sc[1]), fmaxf(sc[2], sc[3])),
                     fmaxf(fmaxf(sc[4], sc[5]), fmaxf(sc[6], sc[7])));
    float pm2 = fmaxf(fmaxf(fmaxf(sc[8], sc[9]), fmaxf(sc[10], sc[11])),
                      fmaxf(fmaxf(sc[12], sc[13]), fmaxf(sc[14], sc[15])));
    pm = fmaxf(pm, pm2);
    pm = fmaxf(pm, __shfl_xor(pm, 32, 64));

    bool defer = (pm <= M + 8.0f);
    if (!__all(defer)) {
      float Mn = fmaxf(M, pm);
      float corr = exp2f(M - Mn);
      M = Mn;
      L *= corr;
#pragma unroll
      for (int r = 0; r < 16; ++r) {
        float cr = __shfl(corr, (r & 3) + 8 * (r >> 2) + 4 * hh, 64);
#pragma unroll
        for (int c = 0; c < 4; ++c) oacc[c][r] *= cr;
      }
    }

#pragma unroll
    for (int r = 0; r < 16; ++r) sc[r] = exp2f(sc[r] - M);
    float rs = ((sc[0] + sc[1]) + (sc[2] + sc[3])) + ((sc[4] + sc[5]) + (sc[6] + sc[7]))
             + ((sc[8] + sc[9]) + (sc[10] + sc[11])) + ((sc[12] + sc[13]) + (sc[14] + sc[15]));
    rs += __shfl_xor(rs, 32, 64);
    L += rs;

    // pack P into PV A-frags and accumulate O
#pragma unroll
    for (int tt = 0; tt < 2; ++tt) {
      unsigned A0 = cvtpk(sc[8 * tt + 0], sc[8 * tt + 1]);
      unsigned A1 = cvtpk(sc[8 * tt + 2], sc[8 * tt + 3]);
      unsigned B0 = cvtpk(sc[8 * tt + 4], sc[8 * tt + 5]);
      unsigned B1 = cvtpk(sc[8 * tt + 6], sc[8 * tt + 7]);
      plswap(A0, B0);
      plswap(A1, B1);
      union { unsigned w[4]; bf16x8 v; } pa;
      pa.w[0] = A0; pa.w[1] = A1; pa.w[2] = B0; pa.w[3] = B1;
      __builtin_amdgcn_s_setprio(1);
#pragma unroll
      for (int c = 0; c < 4; ++c)
        oacc[c] = __builtin_amdgcn_mfma_f32_32x32x16_bf16(pa.v, vf[c][tt], oacc[c], 0, 0, 0);
      __builtin_amdgcn_s_setprio(0);
    }
  }

  // ---- overlay handoff: loop done -> Q buffer dead ----
  __syncthreads();
  if (hh == 0) { mls[wid][l31][0] = M; mls[wid][l31][1] = L; }
  __syncthreads();

  // flash merge over the 4 kv-split partials
  for (int w = 0; w < 4; ++w) {
    if (wid == w) {
#pragma unroll
      for (int r = 0; r < 16; ++r) {
        int q = (r & 3) + 8 * (r >> 2) + 4 * hh;
        float m_own = mls[wid][q][0];   // per-row max from LDS (R20 fix)
        float Mg = fmaxf(fmaxf(mls[0][q][0], mls[1][q][0]),
                         fmaxf(mls[2][q][0], mls[3][q][0]));
        float s = exp2f(m_own - Mg);
#pragma unroll
        for (int c = 0; c < 4; ++c) {
          float v = oacc[c][r] * s;
          if (w == 0) Obuf[q][32 * c + l31] = v;
          else        Obuf[q][32 * c + l31] += v;
        }
      }
    }
    __syncthreads();
  }

  // write-out: wave wid normalizes+stores rows wid*8 .. wid*8+7
#pragma unroll
  for (int rr = 0; rr < 8; ++rr) {
    int row = wid * 8 + rr;
    float Mg = fmaxf(fmaxf(mls[0][row][0], mls[1][row][0]),
                     fmaxf(mls[2][row][0], mls[3][row][0]));
    float lt = 0.f;
#pragma unroll
    for (int w2 = 0; w2 < 4; ++w2)
      lt += exp2f(mls[w2][row][0] - Mg) * mls[w2][row][1];
    float inv = 1.0f / lt;
    float v0 = Obuf[row][lane * 2]     * inv;
    float v1 = Obuf[row][lane * 2 + 1] * inv;
    unsigned pack = (unsigned)f2bf(v0) | ((unsigned)f2bf(v1) << 16);
    *(unsigned*)&ao[(size_t)(q0 + row) * 2048 + h * 128 + lane * 2] = pack;
  }
}

// ---------------------------------------------------------------------------
extern "C" void kernel_launch(void* const* d_in, const int* in_sizes, int n_in,
                              void* d_out, int out_size, void* d_ws, size_t ws_size,
                              hipStream_t stream) {
  const float* x     = (const float*)d_in[0];   // 2048 x 2048 f32
  const float* w_qkv = (const float*)d_in[1];   // 6144 x 2048 f32
  const float* w_out = (const float*)d_in[2];   // 2048 x 2048 f32
  float* out = (float*)d_out;                   // 2048 x 2048 f32
  const int S = 2048, H = 2048, O3 = 6144;

  // workspace (u16 elems), peak 58.8 MB with aliasing:
  u16* qkv     = (u16*)d_ws;                    // S*O3 = 25.2 MB
  u16* x_bf    = qkv + (size_t)S * O3;          //  8.4 MB
  u16* wqkv_bf = x_bf + (size_t)S * H;          // 25.2 MB region
  u16* ao      = x_bf;                          // alias (x_bf dead after GEMM1)
  u16* vt2     = wqkv_bf;                       // alias: 8.4 MB
  u16* kt2     = wqkv_bf + (size_t)H * S;       // alias: 8.4 MB
  u16* wout_bf = wqkv_bf + 2 * (size_t)H * S;   // alias: 8.4 MB (= 25.2 total)

  // 1. convert x and w_qkv to bf16 (single fused launch)
  conv2_f32_bf16<<<(S * H) / 1024 + (O3 * H) / 1024, 256, 0, stream>>>(
      x, x_bf, (S * H) / 1024, w_qkv, wqkv_bf);
  // 2. qkv = x @ w_qkv^T  (M=2048, N=6144, K=2048) -- pipelined 128^2, 768 blocks
  gemm128p_bt<u16><<<(S / 128) * (O3 / 128), 256, 0, stream>>>(x_bf, wqkv_bf, qkv, S, O3, H);
  // 3. RoPE on q,k in place (q pre-scaled by QSCALE)
  rope_qk<<<(S * 2 * 16 * 16) / 256, 256, 0, stream>>>(qkv);
  // 4. repack V and K into per-(h,t) tiles (single fused launch)
  repack_kv<<<dim3(64, 80), 256, 0, stream>>>(qkv, vt2, kt2);
  // 5. convert w_out (into region freed after GEMM1)
  conv_f32_bf16<<<(S * H) / 1024, 256, 0, stream>>>(w_out, wout_bf);
  // 6. causal flash attention (4-wave flat blocks, LPT order) -> ao
  attn_fwd<<<dim3(64, 16), 256, 0, stream>>>(qkv, kt2, vt2, ao);
  // 7. out = ao @ w_out^T  (M=2048, N=2048, K=2048) -- pipelined 128x64,
  //    512 blocks = 2/CU (vs 128^2's 256 = 1/CU), f32 out
  gemm128x64p_bt<float><<<(S / 128) * (H / 64), 256, 0, stream>>>(ao, wout_bf, out, S, H, H);
}

// Round 31
// 162.867 us; speedup vs baseline: 1.2016x; 1.0114x over previous
//
#include <hip/hip_runtime.h>
#include <math.h>

typedef unsigned short u16;
typedef __attribute__((ext_vector_type(4))) float f32x4;
typedef __attribute__((ext_vector_type(16))) float f32x16;
typedef __attribute__((ext_vector_type(4))) unsigned short u16x4;
typedef __attribute__((ext_vector_type(8))) short bf16x8;
typedef __attribute__((ext_vector_type(8))) unsigned short u16x8;

#define LOG2E 1.4426950408889634f
#define QSCALE (0.08838834764831845f * LOG2E)   // 1/sqrt(128) * log2(e)

__device__ __forceinline__ u16 f2bf(float f) {
  union { float f; unsigned u; } v; v.f = f;
  unsigned r = (v.u + 0x7fff + ((v.u >> 16) & 1)) >> 16;
  return (u16)r;
}
__device__ __forceinline__ float bf2f(u16 u) {
  union { unsigned u; float f; } v; v.u = ((unsigned)u) << 16; return v.f;
}
__device__ __forceinline__ void stor(float* C, size_t i, float v) { C[i] = v; }
__device__ __forceinline__ void stor(u16* C, size_t i, float v) { C[i] = f2bf(v); }

__device__ __forceinline__ unsigned cvtpk(float a, float b) {
  unsigned r;
  asm("v_cvt_pk_bf16_f32 %0, %1, %2" : "=v"(r) : "v"(a), "v"(b));
  return r;
}
// swap: a.hi-lanes <-> b.lo-lanes. Operands MUST be distinct values
// (same-value copies may share a register -> self-swap corruption, R17 bug).
__device__ __forceinline__ void plswap(unsigned &a, unsigned &b) {
  asm volatile("v_permlane32_swap_b32 %0, %1" : "+v"(a), "+v"(b));
}

// ---------------------------------------------------------------------------
// Fused f32 -> bf16 conversion of TWO arrays in one launch.
// ---------------------------------------------------------------------------
__global__ void conv2_f32_bf16(const float* __restrict__ a, u16* __restrict__ da,
                               int nblkA, const float* __restrict__ b,
                               u16* __restrict__ db) {
  int blk = blockIdx.x;
  const float* src;
  u16* dst;
  int base;
  if (blk < nblkA) { src = a; dst = da; base = blk; }
  else             { src = b; dst = db; base = blk - nblkA; }
  int i = (base * 256 + threadIdx.x) * 4;
  f32x4 v = *(const f32x4*)(src + i);
  u16x4 o;
#pragma unroll
  for (int j = 0; j < 4; ++j) o[j] = f2bf(v[j]);
  *(u16x4*)(dst + i) = o;
}

__global__ void conv_f32_bf16(const float* __restrict__ src, u16* __restrict__ dst) {
  int i = (blockIdx.x * blockDim.x + threadIdx.x) * 4;
  f32x4 v = *(const f32x4*)(src + i);
  u16x4 o;
#pragma unroll
  for (int j = 0; j < 4; ++j) o[j] = f2bf(v[j]);
  *(u16x4*)(dst + i) = o;
}

// ---------------------------------------------------------------------------
// Pipelined 128x128 GEMM (T3/T4 schedule): BK=64, 4 waves (2x2), dbuf 64KB
// LDS, depth-2 prefetch, counted vmcnt(8), both-sides XOR swizzle. (proven)
// ---------------------------------------------------------------------------
template <typename TOUT>
__global__ __launch_bounds__(256, 1)
void gemm128p_bt(const u16* __restrict__ A, const u16* __restrict__ B,
                 TOUT* __restrict__ C, int M, int N, int K) {
  __shared__ __align__(16) char smem[65536];    // 2 slots x (A 16KB + B 16KB)
  const int tid  = threadIdx.x;
  const int lane = tid & 63;
  const int wid  = tid >> 6;        // 0..3
  const int wr = wid >> 1, wc = wid & 1;
  const int fr = lane & 15, fq = lane >> 4;

  const int nwg = gridDim.x;
  const int wg  = (blockIdx.x & 7) * (nwg >> 3) + (blockIdx.x >> 3);
  const int nrt = M >> 7;
  const int rt  = wg % nrt, ct = wg / nrt;
  const int row0 = rt * 128, col0 = ct * 128;
  const int nt = K >> 6;

#define STAGE128(base, kt)                                                      \
  {                                                                             \
    _Pragma("unroll")                                                           \
    for (int j = 0; j < 4; ++j) {                                               \
      int c   = tid + j * 256;                                                  \
      int row = c >> 3;                                                         \
      int ke  = (((c & 7) ^ (row & 7)) * 8);                                    \
      const u16* sA = A + (size_t)(row0 + row) * K + (kt) * 64 + ke;            \
      __builtin_amdgcn_global_load_lds(                                         \
          (const __attribute__((address_space(1))) void*)sA,                    \
          (__attribute__((address_space(3))) void*)((base) + c * 16), 16, 0, 0);\
      const u16* sB = B + (size_t)(col0 + row) * K + (kt) * 64 + ke;            \
      __builtin_amdgcn_global_load_lds(                                         \
          (const __attribute__((address_space(1))) void*)sB,                    \
          (__attribute__((address_space(3))) void*)((base) + 16384 + c * 16), 16, 0, 0);\
    }                                                                           \
  }

  STAGE128(smem, 0);
  STAGE128(smem + 32768, 1);
  asm volatile("s_waitcnt vmcnt(8)" ::: "memory");   // tile 0 landed
  __builtin_amdgcn_s_barrier();
  __builtin_amdgcn_sched_barrier(0);

  f32x4 acc[4][4] = {};

  for (int t = 0; t < nt; ++t) {
    char* slot = smem + (t & 1) * 32768;

    bf16x8 af[4][2], bf[4][2];
#pragma unroll
    for (int mf = 0; mf < 4; ++mf)
#pragma unroll
      for (int kk = 0; kk < 2; ++kk) {
        int row = wr * 64 + mf * 16 + fr;
        int off = row * 128 + ((kk * 64 + fq * 16) ^ ((row & 7) << 4));
        af[mf][kk] = *(const bf16x8*)(slot + off);
      }
#pragma unroll
    for (int nf = 0; nf < 4; ++nf)
#pragma unroll
      for (int kk = 0; kk < 2; ++kk) {
        int row = wc * 64 + nf * 16 + fr;
        int off = row * 128 + ((kk * 64 + fq * 16) ^ ((row & 7) << 4));
        bf[nf][kk] = *(const bf16x8*)(slot + 16384 + off);
      }
    asm volatile("s_waitcnt lgkmcnt(0)" ::: "memory");
    __builtin_amdgcn_sched_barrier(0);
    __builtin_amdgcn_s_barrier();
    __builtin_amdgcn_sched_barrier(0);

    if (t + 2 < nt) STAGE128(slot, t + 2);
    __builtin_amdgcn_sched_barrier(0);

    __builtin_amdgcn_s_setprio(1);
#pragma unroll
    for (int kk = 0; kk < 2; ++kk)
#pragma unroll
      for (int mf = 0; mf < 4; ++mf)
#pragma unroll
        for (int nf = 0; nf < 4; ++nf)
          acc[mf][nf] = __builtin_amdgcn_mfma_f32_16x16x32_bf16(
              af[mf][kk], bf[nf][kk], acc[mf][nf], 0, 0, 0);
    __builtin_amdgcn_s_setprio(0);

    if (t + 2 < nt) {
      asm volatile("s_waitcnt vmcnt(8)" ::: "memory");
    } else {
      asm volatile("s_waitcnt vmcnt(0)" ::: "memory");
    }
    __builtin_amdgcn_s_barrier();
    __builtin_amdgcn_sched_barrier(0);
  }
#undef STAGE128

#pragma unroll
  for (int mf = 0; mf < 4; ++mf)
#pragma unroll
    for (int nf = 0; nf < 4; ++nf) {
      int row = row0 + wr * 64 + mf * 16 + fq * 4;
      int col = col0 + wc * 64 + nf * 16 + fr;
#pragma unroll
      for (int r = 0; r < 4; ++r)
        stor(C, (size_t)(row + r) * N + col, acc[mf][nf][r]);
    }
}

// ---------------------------------------------------------------------------
// Pipelined 128x64 GEMM (same schedule, shrunk): BK=64, 4 waves (2Mx2N),
// dbuf 48KB LDS, depth-2 prefetch, counted vmcnt(6). (proven, R30)
// ---------------------------------------------------------------------------
template <typename TOUT>
__global__ __launch_bounds__(256, 1)
void gemm128x64p_bt(const u16* __restrict__ A, const u16* __restrict__ B,
                    TOUT* __restrict__ C, int M, int N, int K) {
  __shared__ __align__(16) char smem[49152];    // 2 slots x (A 16KB + B 8KB)
  const int tid  = threadIdx.x;
  const int lane = tid & 63;
  const int wid  = tid >> 6;        // 0..3
  const int wr = wid >> 1, wc = wid & 1;
  const int fr = lane & 15, fq = lane >> 4;

  const int nwg = gridDim.x;
  const int wg  = (blockIdx.x & 7) * (nwg >> 3) + (blockIdx.x >> 3);
  const int nrt = M >> 7;
  const int rt  = wg % nrt, ct = wg / nrt;
  const int row0 = rt * 128, col0 = ct * 64;
  const int nt = K >> 6;

#define STAGE12864(base, kt)                                                    \
  {                                                                             \
    _Pragma("unroll")                                                           \
    for (int j = 0; j < 4; ++j) {      /* A: 128 rows x 64 k = 16KB */          \
      int c   = tid + j * 256;                                                  \
      int row = c >> 3;                                                         \
      int ke  = (((c & 7) ^ (row & 7)) * 8);                                    \
      const u16* sA = A + (size_t)(row0 + row) * K + (kt) * 64 + ke;            \
      __builtin_amdgcn_global_load_lds(                                         \
          (const __attribute__((address_space(1))) void*)sA,                    \
          (__attribute__((address_space(3))) void*)((base) + c * 16), 16, 0, 0);\
    }                                                                           \
    _Pragma("unroll")                                                           \
    for (int j = 0; j < 2; ++j) {      /* B: 64 rows x 64 k = 8KB */            \
      int c   = tid + j * 256;                                                  \
      int row = c >> 3;                                                         \
      int ke  = (((c & 7) ^ (row & 7)) * 8);                                    \
      const u16* sB = B + (size_t)(col0 + row) * K + (kt) * 64 + ke;            \
      __builtin_amdgcn_global_load_lds(                                         \
          (const __attribute__((address_space(1))) void*)sB,                    \
          (__attribute__((address_space(3))) void*)((base) + 16384 + c * 16), 16, 0, 0);\
    }                                                                           \
  }

  STAGE12864(smem, 0);
  STAGE12864(smem + 24576, 1);
  asm volatile("s_waitcnt vmcnt(6)" ::: "memory");   // tile 0 landed
  __builtin_amdgcn_s_barrier();
  __builtin_amdgcn_sched_barrier(0);

  f32x4 acc[4][2] = {};

  for (int t = 0; t < nt; ++t) {
    char* slot = smem + (t & 1) * 24576;

    bf16x8 af[4][2], bf[2][2];
#pragma unroll
    for (int mf = 0; mf < 4; ++mf)
#pragma unroll
      for (int kk = 0; kk < 2; ++kk) {
        int row = wr * 64 + mf * 16 + fr;
        int off = row * 128 + ((kk * 64 + fq * 16) ^ ((row & 7) << 4));
        af[mf][kk] = *(const bf16x8*)(slot + off);
      }
#pragma unroll
    for (int nf = 0; nf < 2; ++nf)
#pragma unroll
      for (int kk = 0; kk < 2; ++kk) {
        int row = wc * 32 + nf * 16 + fr;
        int off = row * 128 + ((kk * 64 + fq * 16) ^ ((row & 7) << 4));
        bf[nf][kk] = *(const bf16x8*)(slot + 16384 + off);
      }
    asm volatile("s_waitcnt lgkmcnt(0)" ::: "memory");
    __builtin_amdgcn_sched_barrier(0);
    __builtin_amdgcn_s_barrier();
    __builtin_amdgcn_sched_barrier(0);

    if (t + 2 < nt) STAGE12864(slot, t + 2);
    __builtin_amdgcn_sched_barrier(0);

    __builtin_amdgcn_s_setprio(1);
#pragma unroll
    for (int kk = 0; kk < 2; ++kk)
#pragma unroll
      for (int mf = 0; mf < 4; ++mf)
#pragma unroll
        for (int nf = 0; nf < 2; ++nf)
          acc[mf][nf] = __builtin_amdgcn_mfma_f32_16x16x32_bf16(
              af[mf][kk], bf[nf][kk], acc[mf][nf], 0, 0, 0);
    __builtin_amdgcn_s_setprio(0);

    if (t + 2 < nt) {
      asm volatile("s_waitcnt vmcnt(6)" ::: "memory");
    } else {
      asm volatile("s_waitcnt vmcnt(0)" ::: "memory");
    }
    __builtin_amdgcn_s_barrier();
    __builtin_amdgcn_sched_barrier(0);
  }
#undef STAGE12864

#pragma unroll
  for (int mf = 0; mf < 4; ++mf)
#pragma unroll
    for (int nf = 0; nf < 2; ++nf) {
      int row = row0 + wr * 64 + mf * 16 + fq * 4;
      int col = col0 + wc * 32 + nf * 16 + fr;
#pragma unroll
      for (int r = 0; r < 4; ++r)
        stor(C, (size_t)(row + r) * N + col, acc[mf][nf][r]);
    }
}

// ---------------------------------------------------------------------------
// RoPE in-place on the Q part of qkv only (K is roped inside repack_kv).
// Q pre-scaled by QSCALE. One thread = 8 bf16 = 4 rotary pairs.
// ---------------------------------------------------------------------------
__global__ void rope_q(u16* qkv) {
  int idx = blockIdx.x * blockDim.x + threadIdx.x;
  int i4 = idx & 15;
  int h  = (idx >> 4) & 15;
  int s  = idx >> 8;
  u16* p = qkv + (size_t)s * 6144 + h * 128 + i4 * 8;
  u16x8 v = *(const u16x8*)p;
  u16x8 w;
#pragma unroll
  for (int j = 0; j < 4; ++j) {
    int i = i4 * 4 + j;
    float inv = exp2f(-(float)i * 0.2076205059304601f);  // 10000^(-i/64)
    float ang = (float)s * inv;
    float sn, cs;
    sincosf(ang, &sn, &cs);
    float e = bf2f(v[2 * j]);
    float o = bf2f(v[2 * j + 1]);
    w[2 * j]     = f2bf((e * cs - o * sn) * QSCALE);
    w[2 * j + 1] = f2bf((e * sn + o * cs) * QSCALE);
  }
  *(u16x8*)p = w;
}

// ---------------------------------------------------------------------------
// Fused repack of V and K into per-(head, kv-tile) 8KB tiles, one launch.
// K path additionally applies RoPE inline (reads PRE-rope K from qkv; kt2 is
// the only K consumer, saving the separate rope read+write pass over K).
// ---------------------------------------------------------------------------
__global__ void repack_kv(const u16* __restrict__ qkv, u16* __restrict__ vt2,
                          u16* __restrict__ kt2) {
  if (blockIdx.y < 64) {
    // ---- V path (unchanged) ----
    __shared__ u16 tile[32][33];
    int s0 = blockIdx.x * 32, c0 = blockIdx.y * 32;
    int tx = threadIdx.x & 31, ty = threadIdx.x >> 5;  // 32 x 8
#pragma unroll
    for (int i = ty; i < 32; i += 8)
      tile[i][tx] = qkv[(size_t)(s0 + i) * 6144 + 4096 + c0 + tx];
    __syncthreads();
    int t = s0 >> 5;
#pragma unroll
    for (int i = ty; i < 32; i += 8) {
      int col = c0 + i;                 // h*128 + d
      int h = col >> 7, d = col & 127;
      int slot = ((d >> 3) << 5) + ((tx >> 3) << 3) + (d & 7);
      vt2[((size_t)(h * 64 + t)) * 4096 + slot * 8 + (tx & 7)] = tile[tx][i];
    }
  } else {
    // ---- K path: repack + RoPE (no QSCALE on K) ----
    int t = blockIdx.x, h = blockIdx.y - 64;
    int j = threadIdx.x >> 3;        // kv row 0..31
    int c = threadIdx.x & 7;         // d-chunk of 16 u16 = 8 rotary pairs
    int s = t * 32 + j;              // global kv position
    const u16* src = qkv + (size_t)s * 6144 + 2048 + h * 128 + c * 16;
    union { u16x8 v[2]; u16 e[16]; } d;
    d.v[0] = *(const u16x8*)src;
    d.v[1] = *(const u16x8*)(src + 8);
#pragma unroll
    for (int m = 0; m < 8; ++m) {
      int i = c * 8 + m;             // pair index 0..63
      float inv = exp2f(-(float)i * 0.2076205059304601f);  // 10000^(-i/64)
      float ang = (float)s * inv;
      float sn, cs;
      sincosf(ang, &sn, &cs);
      float e = bf2f(d.e[2 * m]);
      float o = bf2f(d.e[2 * m + 1]);
      d.e[2 * m]     = f2bf(e * cs - o * sn);
      d.e[2 * m + 1] = f2bf(e * sn + o * cs);
    }
    u16* dst = kt2 + ((size_t)(h * 64 + t)) * 4096 + c * 512 + j * 16;
    *(u16x8*)dst       = d.v[0];
    *(u16x8*)(dst + 8) = d.v[1];
  }
}

// ---------------------------------------------------------------------------
// Causal flash attention: 4-wave FLAT blocks, all-direct K/V, LPT order.
// __launch_bounds__(256, 2): best-measured config (VGPR 96, 73us).
// ---------------------------------------------------------------------------
__global__ __launch_bounds__(256, 2)
void attn_fwd(const u16* __restrict__ qkv, const u16* __restrict__ kt2,
              const u16* __restrict__ vt2, u16* __restrict__ ao) {
  const int f    = blockIdx.y * 64 + blockIdx.x;
  const int h    = ((f & 7) << 1) | ((f >> 3) & 1);  // 2 heads per XCD
  const int tile = 63 - (f >> 4);                     // LPT: longest first
  const int tid  = threadIdx.x;
  const int lane = tid & 63;
  const int wid  = tid >> 6;        // 0..3 = kv-split slot
  const int l31  = lane & 31;
  const int hh   = lane >> 5;
  const int q0 = tile * 32;

  __shared__ __align__(16) char smem[17408];
  char* bufQ = smem;                                       // 8KB, loop phase
  float (*Obuf)[128] = (float(*)[128])smem;                // overlay post-loop (16KB)
  float (*mls)[32][2] = (float(*)[32][2])(smem + 16384);   // overlay post-loop (1KB)

  const char* qkvB = (const char*)qkv;
  const char* ktH = (const char*)kt2 + (size_t)h * 64 * 8192;
  const char* vtH = (const char*)vt2 + (size_t)h * 64 * 8192;

  // ---- prologue: stage shared Q (2 instrs/wave) ----
#pragma unroll
  for (int kk = 0; kk < 2; ++kk) {
    int k = wid * 2 + kk;
    int s = k * 64 + lane;
    int row = ((s >> 7) << 3) | (s & 7);
    int c = (s >> 3) & 15;
    const char* src = qkvB + (size_t)(q0 + row) * 12288 + h * 256 + c * 16;
    __builtin_amdgcn_global_load_lds(
        (const __attribute__((address_space(1))) void*)src,
        (__attribute__((address_space(3))) void*)(bufQ + k * 1024 + lane * 16), 16, 0, 0);
  }
  __syncthreads();   // Q ready

  f32x16 oacc[4] = {};              // q=(r&3)+8*(r>>2)+4*hh, d=32c+l31
  float M = -1e30f, L = 0.f;

  const int qkBase = ((l31 >> 3) << 11) + (hh << 7) + ((l31 & 7) << 4);  // Q: + s*256
  const int vBase  = ((l31 >> 3) << 9)  + (hh << 7) + ((l31 & 7) << 4);  // V: + c*2048 + tt*256
  const int kBase  = l31 * 32 + hh * 16;                                  // K: + s*1024

  for (int t = wid; t <= tile; t += 4) {
    const char* kt = ktH + (size_t)t * 8192;
    const char* vt = vtH + (size_t)t * 8192;

    // V fragments early (consumed at PV -> latency hidden by design)
    bf16x8 vf[4][2];
#pragma unroll
    for (int c = 0; c < 4; ++c)
#pragma unroll
      for (int tt = 0; tt < 2; ++tt)
        vf[c][tt] = *(const bf16x8*)(vt + vBase + c * 2048 + tt * 256);

    // QK^T swapped: A = K rows (direct), B = Q rows (LDS); S[kv][q], q = l31
    f32x16 sc = {};
    {
      bf16x8 ka[4], qa[4];
#pragma unroll
      for (int s = 0; s < 4; ++s) {
        ka[s] = *(const bf16x8*)(kt + kBase + s * 1024);
        qa[s] = *(const bf16x8*)(bufQ + qkBase + s * 256);
      }
      __builtin_amdgcn_s_setprio(1);
#pragma unroll
      for (int s = 0; s < 4; ++s)
        sc = __builtin_amdgcn_mfma_f32_32x32x16_bf16(ka[s], qa[s], sc, 0, 0, 0);
      __builtin_amdgcn_s_setprio(0);
#pragma unroll
      for (int s = 0; s < 4; ++s) {
        ka[s] = *(const bf16x8*)(kt + kBase + (s + 4) * 1024);
        qa[s] = *(const bf16x8*)(bufQ + qkBase + (s + 4) * 256);
      }
      __builtin_amdgcn_s_setprio(1);
#pragma unroll
      for (int s = 0; s < 4; ++s)
        sc = __builtin_amdgcn_mfma_f32_32x32x16_bf16(ka[s], qa[s], sc, 0, 0, 0);
      __builtin_amdgcn_s_setprio(0);
    }

    // causal mask on the diagonal tile
    if (t == tile) {
#pragma unroll
      for (int r = 0; r < 16; ++r) {
        int kv = (r & 3) + 8 * (r >> 2) + 4 * hh;
        if (kv > l31) sc[r] = -1e30f;
      }
    }

    // per-lane online softmax, T13 defer-max
    float pm = fmaxf(fmaxf(fmaxf(sc[0], sc[1]), fmaxf(sc[2], sc[3])),
                     fmaxf(fmaxf(sc[4], sc[5]), fmaxf(sc[6], sc[7])));
    float pm2 = fmaxf(fmaxf(fmaxf(sc[8], sc[9]), fmaxf(sc[10], sc[11])),
                      fmaxf(fmaxf(sc[12], sc[13]), fmaxf(sc[14], sc[15])));
    pm = fmaxf(pm, pm2);
    pm = fmaxf(pm, __shfl_xor(pm, 32, 64));

    bool defer = (pm <= M + 8.0f);
    if (!__all(defer)) {
      float Mn = fmaxf(M, pm);
      float corr = exp2f(M - Mn);
      M = Mn;
      L *= corr;
#pragma unroll
      for (int r = 0; r < 16; ++r) {
        float cr = __shfl(corr, (r & 3) + 8 * (r >> 2) + 4 * hh, 64);
#pragma unroll
        for (int c = 0; c < 4; ++c) oacc[c][r] *= cr;
      }
    }

#pragma unroll
    for (int r = 0; r < 16; ++r) sc[r] = exp2f(sc[r] - M);
    float rs = ((sc[0] + sc[1]) + (sc[2] + sc[3])) + ((sc[4] + sc[5]) + (sc[6] + sc[7]))
             + ((sc[8] + sc[9]) + (sc[10] + sc[11])) + ((sc[12] + sc[13]) + (sc[14] + sc[15]));
    rs += __shfl_xor(rs, 32, 64);
    L += rs;

    // pack P into PV A-frags and accumulate O
#pragma unroll
    for (int tt = 0; tt < 2; ++tt) {
      unsigned A0 = cvtpk(sc[8 * tt + 0], sc[8 * tt + 1]);
      unsigned A1 = cvtpk(sc[8 * tt + 2], sc[8 * tt + 3]);
      unsigned B0 = cvtpk(sc[8 * tt + 4], sc[8 * tt + 5]);
      unsigned B1 = cvtpk(sc[8 * tt + 6], sc[8 * tt + 7]);
      plswap(A0, B0);
      plswap(A1, B1);
      union { unsigned w[4]; bf16x8 v; } pa;
      pa.w[0] = A0; pa.w[1] = A1; pa.w[2] = B0; pa.w[3] = B1;
      __builtin_amdgcn_s_setprio(1);
#pragma unroll
      for (int c = 0; c < 4; ++c)
        oacc[c] = __builtin_amdgcn_mfma_f32_32x32x16_bf16(pa.v, vf[c][tt], oacc[c], 0, 0, 0);
      __builtin_amdgcn_s_setprio(0);
    }
  }

  // ---- overlay handoff: loop done -> Q buffer dead ----
  __syncthreads();
  if (hh == 0) { mls[wid][l31][0] = M; mls[wid][l31][1] = L; }
  __syncthreads();

  // flash merge over the 4 kv-split partials
  for (int w = 0; w < 4; ++w) {
    if (wid == w) {
#pragma unroll
      for (int r = 0; r < 16; ++r) {
        int q = (r & 3) + 8 * (r >> 2) + 4 * hh;
        float m_own = mls[wid][q][0];   // per-row max from LDS (R20 fix)
        float Mg = fmaxf(fmaxf(mls[0][q][0], mls[1][q][0]),
                         fmaxf(mls[2][q][0], mls[3][q][0]));
        float s = exp2f(m_own - Mg);
#pragma unroll
        for (int c = 0; c < 4; ++c) {
          float v = oacc[c][r] * s;
          if (w == 0) Obuf[q][32 * c + l31] = v;
          else        Obuf[q][32 * c + l31] += v;
        }
      }
    }
    __syncthreads();
  }

  // write-out: wave wid normalizes+stores rows wid*8 .. wid*8+7
#pragma unroll
  for (int rr = 0; rr < 8; ++rr) {
    int row = wid * 8 + rr;
    float Mg = fmaxf(fmaxf(mls[0][row][0], mls[1][row][0]),
                     fmaxf(mls[2][row][0], mls[3][row][0]));
    float lt = 0.f;
#pragma unroll
    for (int w2 = 0; w2 < 4; ++w2)
      lt += exp2f(mls[w2][row][0] - Mg) * mls[w2][row][1];
    float inv = 1.0f / lt;
    float v0 = Obuf[row][lane * 2]     * inv;
    float v1 = Obuf[row][lane * 2 + 1] * inv;
    unsigned pack = (unsigned)f2bf(v0) | ((unsigned)f2bf(v1) << 16);
    *(unsigned*)&ao[(size_t)(q0 + row) * 2048 + h * 128 + lane * 2] = pack;
  }
}

// ---------------------------------------------------------------------------
extern "C" void kernel_launch(void* const* d_in, const int* in_sizes, int n_in,
                              void* d_out, int out_size, void* d_ws, size_t ws_size,
                              hipStream_t stream) {
  const float* x     = (const float*)d_in[0];   // 2048 x 2048 f32
  const float* w_qkv = (const float*)d_in[1];   // 6144 x 2048 f32
  const float* w_out = (const float*)d_in[2];   // 2048 x 2048 f32
  float* out = (float*)d_out;                   // 2048 x 2048 f32
  const int S = 2048, H = 2048, O3 = 6144;

  // workspace (u16 elems), peak 58.8 MB with aliasing:
  u16* qkv     = (u16*)d_ws;                    // S*O3 = 25.2 MB
  u16* x_bf    = qkv + (size_t)S * O3;          //  8.4 MB
  u16* wqkv_bf = x_bf + (size_t)S * H;          // 25.2 MB region
  u16* ao      = x_bf;                          // alias (x_bf dead after GEMM1)
  u16* vt2     = wqkv_bf;                       // alias: 8.4 MB
  u16* kt2     = wqkv_bf + (size_t)H * S;       // alias: 8.4 MB
  u16* wout_bf = wqkv_bf + 2 * (size_t)H * S;   // alias: 8.4 MB (= 25.2 total)

  // 1. convert x and w_qkv to bf16 (single fused launch)
  conv2_f32_bf16<<<(S * H) / 1024 + (O3 * H) / 1024, 256, 0, stream>>>(
      x, x_bf, (S * H) / 1024, w_qkv, wqkv_bf);
  // 2. qkv = x @ w_qkv^T  (M=2048, N=6144, K=2048) -- pipelined 128^2, 768 blocks
  gemm128p_bt<u16><<<(S / 128) * (O3 / 128), 256, 0, stream>>>(x_bf, wqkv_bf, qkv, S, O3, H);
  // 3. RoPE on Q only (K is roped inside repack_kv)
  rope_q<<<(S * 16 * 16) / 256, 256, 0, stream>>>(qkv);
  // 4. repack V and rope+repack K into per-(h,t) tiles (single fused launch)
  repack_kv<<<dim3(64, 80), 256, 0, stream>>>(qkv, vt2, kt2);
  // 5. convert w_out (into region freed after GEMM1)
  conv_f32_bf16<<<(S * H) / 1024, 256, 0, stream>>>(w_out, wout_bf);
  // 6. causal flash attention (4-wave flat blocks, LPT order) -> ao
  attn_fwd<<<dim3(64, 16), 256, 0, stream>>>(qkv, kt2, vt2, ao);
  // 7. out = ao @ w_out^T  (M=2048, N=2048, K=2048) -- pipelined 128x64, f32 out
  gemm128x64p_bt<float><<<(S / 128) * (H / 64), 256, 0, stream>>>(ao, wout_bf, out, S, H, H);
}

// Round 32
// 157.445 us; speedup vs baseline: 1.2429x; 1.0344x over previous
//
#include <hip/hip_runtime.h>
#include <math.h>

typedef unsigned short u16;
typedef __attribute__((ext_vector_type(4))) float f32x4;
typedef __attribute__((ext_vector_type(16))) float f32x16;
typedef __attribute__((ext_vector_type(4))) unsigned short u16x4;
typedef __attribute__((ext_vector_type(8))) short bf16x8;
typedef __attribute__((ext_vector_type(8))) unsigned short u16x8;

#define LOG2E 1.4426950408889634f
#define QSCALE (0.08838834764831845f * LOG2E)   // 1/sqrt(128) * log2(e)

__device__ __forceinline__ u16 f2bf(float f) {
  union { float f; unsigned u; } v; v.f = f;
  unsigned r = (v.u + 0x7fff + ((v.u >> 16) & 1)) >> 16;
  return (u16)r;
}
__device__ __forceinline__ float bf2f(u16 u) {
  union { unsigned u; float f; } v; v.u = ((unsigned)u) << 16; return v.f;
}
__device__ __forceinline__ void stor(float* C, size_t i, float v) { C[i] = v; }
__device__ __forceinline__ void stor(u16* C, size_t i, float v) { C[i] = f2bf(v); }

__device__ __forceinline__ unsigned cvtpk(float a, float b) {
  unsigned r;
  asm("v_cvt_pk_bf16_f32 %0, %1, %2" : "=v"(r) : "v"(a), "v"(b));
  return r;
}
// swap: a.hi-lanes <-> b.lo-lanes. Operands MUST be distinct values
// (same-value copies may share a register -> self-swap corruption, R17 bug).
__device__ __forceinline__ void plswap(unsigned &a, unsigned &b) {
  asm volatile("v_permlane32_swap_b32 %0, %1" : "+v"(a), "+v"(b));
}

// ---------------------------------------------------------------------------
// Fused f32 -> bf16 conversion of TWO arrays in one launch.
// ---------------------------------------------------------------------------
__global__ void conv2_f32_bf16(const float* __restrict__ a, u16* __restrict__ da,
                               int nblkA, const float* __restrict__ b,
                               u16* __restrict__ db) {
  int blk = blockIdx.x;
  const float* src;
  u16* dst;
  int base;
  if (blk < nblkA) { src = a; dst = da; base = blk; }
  else             { src = b; dst = db; base = blk - nblkA; }
  int i = (base * 256 + threadIdx.x) * 4;
  f32x4 v = *(const f32x4*)(src + i);
  u16x4 o;
#pragma unroll
  for (int j = 0; j < 4; ++j) o[j] = f2bf(v[j]);
  *(u16x4*)(dst + i) = o;
}

// ---------------------------------------------------------------------------
// Pipelined 128x128 GEMM (T3/T4 schedule): BK=64, 4 waves (2x2), dbuf 64KB
// LDS, depth-2 prefetch, counted vmcnt(8), both-sides XOR swizzle. (proven)
// ---------------------------------------------------------------------------
template <typename TOUT>
__global__ __launch_bounds__(256, 1)
void gemm128p_bt(const u16* __restrict__ A, const u16* __restrict__ B,
                 TOUT* __restrict__ C, int M, int N, int K) {
  __shared__ __align__(16) char smem[65536];    // 2 slots x (A 16KB + B 16KB)
  const int tid  = threadIdx.x;
  const int lane = tid & 63;
  const int wid  = tid >> 6;        // 0..3
  const int wr = wid >> 1, wc = wid & 1;
  const int fr = lane & 15, fq = lane >> 4;

  const int nwg = gridDim.x;
  const int wg  = (blockIdx.x & 7) * (nwg >> 3) + (blockIdx.x >> 3);
  const int nrt = M >> 7;
  const int rt  = wg % nrt, ct = wg / nrt;
  const int row0 = rt * 128, col0 = ct * 128;
  const int nt = K >> 6;

#define STAGE128(base, kt)                                                      \
  {                                                                             \
    _Pragma("unroll")                                                           \
    for (int j = 0; j < 4; ++j) {                                               \
      int c   = tid + j * 256;                                                  \
      int row = c >> 3;                                                         \
      int ke  = (((c & 7) ^ (row & 7)) * 8);                                    \
      const u16* sA = A + (size_t)(row0 + row) * K + (kt) * 64 + ke;            \
      __builtin_amdgcn_global_load_lds(                                         \
          (const __attribute__((address_space(1))) void*)sA,                    \
          (__attribute__((address_space(3))) void*)((base) + c * 16), 16, 0, 0);\
      const u16* sB = B + (size_t)(col0 + row) * K + (kt) * 64 + ke;            \
      __builtin_amdgcn_global_load_lds(                                         \
          (const __attribute__((address_space(1))) void*)sB,                    \
          (__attribute__((address_space(3))) void*)((base) + 16384 + c * 16), 16, 0, 0);\
    }                                                                           \
  }

  STAGE128(smem, 0);
  STAGE128(smem + 32768, 1);
  asm volatile("s_waitcnt vmcnt(8)" ::: "memory");   // tile 0 landed
  __builtin_amdgcn_s_barrier();
  __builtin_amdgcn_sched_barrier(0);

  f32x4 acc[4][4] = {};

  for (int t = 0; t < nt; ++t) {
    char* slot = smem + (t & 1) * 32768;

    bf16x8 af[4][2], bf[4][2];
#pragma unroll
    for (int mf = 0; mf < 4; ++mf)
#pragma unroll
      for (int kk = 0; kk < 2; ++kk) {
        int row = wr * 64 + mf * 16 + fr;
        int off = row * 128 + ((kk * 64 + fq * 16) ^ ((row & 7) << 4));
        af[mf][kk] = *(const bf16x8*)(slot + off);
      }
#pragma unroll
    for (int nf = 0; nf < 4; ++nf)
#pragma unroll
      for (int kk = 0; kk < 2; ++kk) {
        int row = wc * 64 + nf * 16 + fr;
        int off = row * 128 + ((kk * 64 + fq * 16) ^ ((row & 7) << 4));
        bf[nf][kk] = *(const bf16x8*)(slot + 16384 + off);
      }
    asm volatile("s_waitcnt lgkmcnt(0)" ::: "memory");
    __builtin_amdgcn_sched_barrier(0);
    __builtin_amdgcn_s_barrier();
    __builtin_amdgcn_sched_barrier(0);

    if (t + 2 < nt) STAGE128(slot, t + 2);
    __builtin_amdgcn_sched_barrier(0);

    __builtin_amdgcn_s_setprio(1);
#pragma unroll
    for (int kk = 0; kk < 2; ++kk)
#pragma unroll
      for (int mf = 0; mf < 4; ++mf)
#pragma unroll
        for (int nf = 0; nf < 4; ++nf)
          acc[mf][nf] = __builtin_amdgcn_mfma_f32_16x16x32_bf16(
              af[mf][kk], bf[nf][kk], acc[mf][nf], 0, 0, 0);
    __builtin_amdgcn_s_setprio(0);

    if (t + 2 < nt) {
      asm volatile("s_waitcnt vmcnt(8)" ::: "memory");
    } else {
      asm volatile("s_waitcnt vmcnt(0)" ::: "memory");
    }
    __builtin_amdgcn_s_barrier();
    __builtin_amdgcn_sched_barrier(0);
  }
#undef STAGE128

#pragma unroll
  for (int mf = 0; mf < 4; ++mf)
#pragma unroll
    for (int nf = 0; nf < 4; ++nf) {
      int row = row0 + wr * 64 + mf * 16 + fq * 4;
      int col = col0 + wc * 64 + nf * 16 + fr;
#pragma unroll
      for (int r = 0; r < 4; ++r)
        stor(C, (size_t)(row + r) * N + col, acc[mf][nf][r]);
    }
}

// ---------------------------------------------------------------------------
// Pipelined 128x64 GEMM (same schedule, shrunk): BK=64, 4 waves (2Mx2N),
// dbuf 48KB LDS, depth-2 prefetch, counted vmcnt(6). (proven, R30)
// ---------------------------------------------------------------------------
template <typename TOUT>
__global__ __launch_bounds__(256, 1)
void gemm128x64p_bt(const u16* __restrict__ A, const u16* __restrict__ B,
                    TOUT* __restrict__ C, int M, int N, int K) {
  __shared__ __align__(16) char smem[49152];    // 2 slots x (A 16KB + B 8KB)
  const int tid  = threadIdx.x;
  const int lane = tid & 63;
  const int wid  = tid >> 6;        // 0..3
  const int wr = wid >> 1, wc = wid & 1;
  const int fr = lane & 15, fq = lane >> 4;

  const int nwg = gridDim.x;
  const int wg  = (blockIdx.x & 7) * (nwg >> 3) + (blockIdx.x >> 3);
  const int nrt = M >> 7;
  const int rt  = wg % nrt, ct = wg / nrt;
  const int row0 = rt * 128, col0 = ct * 64;
  const int nt = K >> 6;

#define STAGE12864(base, kt)                                                    \
  {                                                                             \
    _Pragma("unroll")                                                           \
    for (int j = 0; j < 4; ++j) {      /* A: 128 rows x 64 k = 16KB */          \
      int c   = tid + j * 256;                                                  \
      int row = c >> 3;                                                         \
      int ke  = (((c & 7) ^ (row & 7)) * 8);                                    \
      const u16* sA = A + (size_t)(row0 + row) * K + (kt) * 64 + ke;            \
      __builtin_amdgcn_global_load_lds(                                         \
          (const __attribute__((address_space(1))) void*)sA,                    \
          (__attribute__((address_space(3))) void*)((base) + c * 16), 16, 0, 0);\
    }                                                                           \
    _Pragma("unroll")                                                           \
    for (int j = 0; j < 2; ++j) {      /* B: 64 rows x 64 k = 8KB */            \
      int c   = tid + j * 256;                                                  \
      int row = c >> 3;                                                         \
      int ke  = (((c & 7) ^ (row & 7)) * 8);                                    \
      const u16* sB = B + (size_t)(col0 + row) * K + (kt) * 64 + ke;            \
      __builtin_amdgcn_global_load_lds(                                         \
          (const __attribute__((address_space(1))) void*)sB,                    \
          (__attribute__((address_space(3))) void*)((base) + 16384 + c * 16), 16, 0, 0);\
    }                                                                           \
  }

  STAGE12864(smem, 0);
  STAGE12864(smem + 24576, 1);
  asm volatile("s_waitcnt vmcnt(6)" ::: "memory");   // tile 0 landed
  __builtin_amdgcn_s_barrier();
  __builtin_amdgcn_sched_barrier(0);

  f32x4 acc[4][2] = {};

  for (int t = 0; t < nt; ++t) {
    char* slot = smem + (t & 1) * 24576;

    bf16x8 af[4][2], bf[2][2];
#pragma unroll
    for (int mf = 0; mf < 4; ++mf)
#pragma unroll
      for (int kk = 0; kk < 2; ++kk) {
        int row = wr * 64 + mf * 16 + fr;
        int off = row * 128 + ((kk * 64 + fq * 16) ^ ((row & 7) << 4));
        af[mf][kk] = *(const bf16x8*)(slot + off);
      }
#pragma unroll
    for (int nf = 0; nf < 2; ++nf)
#pragma unroll
      for (int kk = 0; kk < 2; ++kk) {
        int row = wc * 32 + nf * 16 + fr;
        int off = row * 128 + ((kk * 64 + fq * 16) ^ ((row & 7) << 4));
        bf[nf][kk] = *(const bf16x8*)(slot + 16384 + off);
      }
    asm volatile("s_waitcnt lgkmcnt(0)" ::: "memory");
    __builtin_amdgcn_sched_barrier(0);
    __builtin_amdgcn_s_barrier();
    __builtin_amdgcn_sched_barrier(0);

    if (t + 2 < nt) STAGE12864(slot, t + 2);
    __builtin_amdgcn_sched_barrier(0);

    __builtin_amdgcn_s_setprio(1);
#pragma unroll
    for (int kk = 0; kk < 2; ++kk)
#pragma unroll
      for (int mf = 0; mf < 4; ++mf)
#pragma unroll
        for (int nf = 0; nf < 2; ++nf)
          acc[mf][nf] = __builtin_amdgcn_mfma_f32_16x16x32_bf16(
              af[mf][kk], bf[nf][kk], acc[mf][nf], 0, 0, 0);
    __builtin_amdgcn_s_setprio(0);

    if (t + 2 < nt) {
      asm volatile("s_waitcnt vmcnt(6)" ::: "memory");
    } else {
      asm volatile("s_waitcnt vmcnt(0)" ::: "memory");
    }
    __builtin_amdgcn_s_barrier();
    __builtin_amdgcn_sched_barrier(0);
  }
#undef STAGE12864

#pragma unroll
  for (int mf = 0; mf < 4; ++mf)
#pragma unroll
    for (int nf = 0; nf < 2; ++nf) {
      int row = row0 + wr * 64 + mf * 16 + fq * 4;
      int col = col0 + wc * 32 + nf * 16 + fr;
#pragma unroll
      for (int r = 0; r < 4; ++r)
        stor(C, (size_t)(row + r) * N + col, acc[mf][nf][r]);
    }
}

// ---------------------------------------------------------------------------
// MEGA repack: one launch does (a) V repack, (b) K rope+repack, (c) Q rope
// in place, (d) w_out f32->bf16 conversion. All four strata touch disjoint
// data and only require GEMM1 complete. Grid (64, 176):
//   y in [0,64)    : V path (x = s-tile, y = col-tile)
//   y in [64,80)   : K path, h = y-64, t = x (rope inline, no QSCALE)
//   y in [80,112)  : Q rope in place, flat block = (y-80)*64 + x  (2048 blks)
//   y in [112,176) : w_out conv,      flat block = (y-112)*64 + x (4096 blks)
// Bodies byte-identical to the individually-proven kernels.
// ---------------------------------------------------------------------------
__global__ void repack_mega(const u16* __restrict__ qkv, u16* __restrict__ vt2,
                            u16* __restrict__ kt2, u16* __restrict__ qkv_mut,
                            const float* __restrict__ w_out,
                            u16* __restrict__ wout_bf) {
  if (blockIdx.y < 64) {
    // ---- V path ----
    __shared__ u16 tile[32][33];
    int s0 = blockIdx.x * 32, c0 = blockIdx.y * 32;
    int tx = threadIdx.x & 31, ty = threadIdx.x >> 5;  // 32 x 8
#pragma unroll
    for (int i = ty; i < 32; i += 8)
      tile[i][tx] = qkv[(size_t)(s0 + i) * 6144 + 4096 + c0 + tx];
    __syncthreads();
    int t = s0 >> 5;
#pragma unroll
    for (int i = ty; i < 32; i += 8) {
      int col = c0 + i;                 // h*128 + d
      int h = col >> 7, d = col & 127;
      int slot = ((d >> 3) << 5) + ((tx >> 3) << 3) + (d & 7);
      vt2[((size_t)(h * 64 + t)) * 4096 + slot * 8 + (tx & 7)] = tile[tx][i];
    }
  } else if (blockIdx.y < 80) {
    // ---- K path: repack + RoPE (no QSCALE on K) ----
    int t = blockIdx.x, h = blockIdx.y - 64;
    int j = threadIdx.x >> 3;        // kv row 0..31
    int c = threadIdx.x & 7;         // d-chunk of 16 u16 = 8 rotary pairs
    int s = t * 32 + j;              // global kv position
    const u16* src = qkv + (size_t)s * 6144 + 2048 + h * 128 + c * 16;
    union { u16x8 v[2]; u16 e[16]; } d;
    d.v[0] = *(const u16x8*)src;
    d.v[1] = *(const u16x8*)(src + 8);
#pragma unroll
    for (int m = 0; m < 8; ++m) {
      int i = c * 8 + m;             // pair index 0..63
      float inv = exp2f(-(float)i * 0.2076205059304601f);  // 10000^(-i/64)
      float ang = (float)s * inv;
      float sn, cs;
      sincosf(ang, &sn, &cs);
      float e = bf2f(d.e[2 * m]);
      float o = bf2f(d.e[2 * m + 1]);
      d.e[2 * m]     = f2bf(e * cs - o * sn);
      d.e[2 * m + 1] = f2bf(e * sn + o * cs);
    }
    u16* dst = kt2 + ((size_t)(h * 64 + t)) * 4096 + c * 512 + j * 16;
    *(u16x8*)dst       = d.v[0];
    *(u16x8*)(dst + 8) = d.v[1];
  } else if (blockIdx.y < 112) {
    // ---- Q rope in place (with QSCALE) ----
    int flat = (blockIdx.y - 80) * 64 + blockIdx.x;   // 0..2047
    int idx = flat * 256 + threadIdx.x;
    int i4 = idx & 15;
    int h  = (idx >> 4) & 15;
    int s  = idx >> 8;
    u16* p = qkv_mut + (size_t)s * 6144 + h * 128 + i4 * 8;
    u16x8 v = *(const u16x8*)p;
    u16x8 w;
#pragma unroll
    for (int j = 0; j < 4; ++j) {
      int i = i4 * 4 + j;
      float inv = exp2f(-(float)i * 0.2076205059304601f);  // 10000^(-i/64)
      float ang = (float)s * inv;
      float sn, cs;
      sincosf(ang, &sn, &cs);
      float e = bf2f(v[2 * j]);
      float o = bf2f(v[2 * j + 1]);
      w[2 * j]     = f2bf((e * cs - o * sn) * QSCALE);
      w[2 * j + 1] = f2bf((e * sn + o * cs) * QSCALE);
    }
    *(u16x8*)p = w;
  } else {
    // ---- w_out f32 -> bf16 ----
    int flat = (blockIdx.y - 112) * 64 + blockIdx.x;  // 0..4095
    int i = (flat * 256 + threadIdx.x) * 4;
    f32x4 v = *(const f32x4*)(w_out + i);
    u16x4 o;
#pragma unroll
    for (int j = 0; j < 4; ++j) o[j] = f2bf(v[j]);
    *(u16x4*)(wout_bf + i) = o;
  }
}

// ---------------------------------------------------------------------------
// Causal flash attention: 4-wave FLAT blocks, all-direct K/V, LPT order.
// __launch_bounds__(256, 2): best-measured config (VGPR 96, 73us).
// ---------------------------------------------------------------------------
__global__ __launch_bounds__(256, 2)
void attn_fwd(const u16* __restrict__ qkv, const u16* __restrict__ kt2,
              const u16* __restrict__ vt2, u16* __restrict__ ao) {
  const int f    = blockIdx.y * 64 + blockIdx.x;
  const int h    = ((f & 7) << 1) | ((f >> 3) & 1);  // 2 heads per XCD
  const int tile = 63 - (f >> 4);                     // LPT: longest first
  const int tid  = threadIdx.x;
  const int lane = tid & 63;
  const int wid  = tid >> 6;        // 0..3 = kv-split slot
  const int l31  = lane & 31;
  const int hh   = lane >> 5;
  const int q0 = tile * 32;

  __shared__ __align__(16) char smem[17408];
  char* bufQ = smem;                                       // 8KB, loop phase
  float (*Obuf)[128] = (float(*)[128])smem;                // overlay post-loop (16KB)
  float (*mls)[32][2] = (float(*)[32][2])(smem + 16384);   // overlay post-loop (1KB)

  const char* qkvB = (const char*)qkv;
  const char* ktH = (const char*)kt2 + (size_t)h * 64 * 8192;
  const char* vtH = (const char*)vt2 + (size_t)h * 64 * 8192;

  // ---- prologue: stage shared Q (2 instrs/wave) ----
#pragma unroll
  for (int kk = 0; kk < 2; ++kk) {
    int k = wid * 2 + kk;
    int s = k * 64 + lane;
    int row = ((s >> 7) << 3) | (s & 7);
    int c = (s >> 3) & 15;
    const char* src = qkvB + (size_t)(q0 + row) * 12288 + h * 256 + c * 16;
    __builtin_amdgcn_global_load_lds(
        (const __attribute__((address_space(1))) void*)src,
        (__attribute__((address_space(3))) void*)(bufQ + k * 1024 + lane * 16), 16, 0, 0);
  }
  __syncthreads();   // Q ready

  f32x16 oacc[4] = {};              // q=(r&3)+8*(r>>2)+4*hh, d=32c+l31
  float M = -1e30f, L = 0.f;

  const int qkBase = ((l31 >> 3) << 11) + (hh << 7) + ((l31 & 7) << 4);  // Q: + s*256
  const int vBase  = ((l31 >> 3) << 9)  + (hh << 7) + ((l31 & 7) << 4);  // V: + c*2048 + tt*256
  const int kBase  = l31 * 32 + hh * 16;                                  // K: + s*1024

  for (int t = wid; t <= tile; t += 4) {
    const char* kt = ktH + (size_t)t * 8192;
    const char* vt = vtH + (size_t)t * 8192;

    // V fragments early (consumed at PV -> latency hidden by design)
    bf16x8 vf[4][2];
#pragma unroll
    for (int c = 0; c < 4; ++c)
#pragma unroll
      for (int tt = 0; tt < 2; ++tt)
        vf[c][tt] = *(const bf16x8*)(vt + vBase + c * 2048 + tt * 256);

    // QK^T swapped: A = K rows (direct), B = Q rows (LDS); S[kv][q], q = l31
    f32x16 sc = {};
    {
      bf16x8 ka[4], qa[4];
#pragma unroll
      for (int s = 0; s < 4; ++s) {
        ka[s] = *(const bf16x8*)(kt + kBase + s * 1024);
        qa[s] = *(const bf16x8*)(bufQ + qkBase + s * 256);
      }
      __builtin_amdgcn_s_setprio(1);
#pragma unroll
      for (int s = 0; s < 4; ++s)
        sc = __builtin_amdgcn_mfma_f32_32x32x16_bf16(ka[s], qa[s], sc, 0, 0, 0);
      __builtin_amdgcn_s_setprio(0);
#pragma unroll
      for (int s = 0; s < 4; ++s) {
        ka[s] = *(const bf16x8*)(kt + kBase + (s + 4) * 1024);
        qa[s] = *(const bf16x8*)(bufQ + qkBase + (s + 4) * 256);
      }
      __builtin_amdgcn_s_setprio(1);
#pragma unroll
      for (int s = 0; s < 4; ++s)
        sc = __builtin_amdgcn_mfma_f32_32x32x16_bf16(ka[s], qa[s], sc, 0, 0, 0);
      __builtin_amdgcn_s_setprio(0);
    }

    // causal mask on the diagonal tile
    if (t == tile) {
#pragma unroll
      for (int r = 0; r < 16; ++r) {
        int kv = (r & 3) + 8 * (r >> 2) + 4 * hh;
        if (kv > l31) sc[r] = -1e30f;
      }
    }

    // per-lane online softmax, T13 defer-max
    float pm = fmaxf(fmaxf(fmaxf(sc[0], sc[1]), fmaxf(sc[2], sc[3])),
                     fmaxf(fmaxf(sc[4], sc[5]), fmaxf(sc[6], sc[7])));
    float pm2 = fmaxf(fmaxf(fmaxf(sc[8], sc[9]), fmaxf(sc[10], sc[11])),
                      fmaxf(fmaxf(sc[12], sc[13]), fmaxf(sc[14], sc[15])));
    pm = fmaxf(pm, pm2);
    pm = fmaxf(pm, __shfl_xor(pm, 32, 64));

    bool defer = (pm <= M + 8.0f);
    if (!__all(defer)) {
      float Mn = fmaxf(M, pm);
      float corr = exp2f(M - Mn);
      M = Mn;
      L *= corr;
#pragma unroll
      for (int r = 0; r < 16; ++r) {
        float cr = __shfl(corr, (r & 3) + 8 * (r >> 2) + 4 * hh, 64);
#pragma unroll
        for (int c = 0; c < 4; ++c) oacc[c][r] *= cr;
      }
    }

#pragma unroll
    for (int r = 0; r < 16; ++r) sc[r] = exp2f(sc[r] - M);
    float rs = ((sc[0] + sc[1]) + (sc[2] + sc[3])) + ((sc[4] + sc[5]) + (sc[6] + sc[7]))
             + ((sc[8] + sc[9]) + (sc[10] + sc[11])) + ((sc[12] + sc[13]) + (sc[14] + sc[15]));
    rs += __shfl_xor(rs, 32, 64);
    L += rs;

    // pack P into PV A-frags and accumulate O
#pragma unroll
    for (int tt = 0; tt < 2; ++tt) {
      unsigned A0 = cvtpk(sc[8 * tt + 0], sc[8 * tt + 1]);
      unsigned A1 = cvtpk(sc[8 * tt + 2], sc[8 * tt + 3]);
      unsigned B0 = cvtpk(sc[8 * tt + 4], sc[8 * tt + 5]);
      unsigned B1 = cvtpk(sc[8 * tt + 6], sc[8 * tt + 7]);
      plswap(A0, B0);
      plswap(A1, B1);
      union { unsigned w[4]; bf16x8 v; } pa;
      pa.w[0] = A0; pa.w[1] = A1; pa.w[2] = B0; pa.w[3] = B1;
      __builtin_amdgcn_s_setprio(1);
#pragma unroll
      for (int c = 0; c < 4; ++c)
        oacc[c] = __builtin_amdgcn_mfma_f32_32x32x16_bf16(pa.v, vf[c][tt], oacc[c], 0, 0, 0);
      __builtin_amdgcn_s_setprio(0);
    }
  }

  // ---- overlay handoff: loop done -> Q buffer dead ----
  __syncthreads();
  if (hh == 0) { mls[wid][l31][0] = M; mls[wid][l31][1] = L; }
  __syncthreads();

  // flash merge over the 4 kv-split partials
  for (int w = 0; w < 4; ++w) {
    if (wid == w) {
#pragma unroll
      for (int r = 0; r < 16; ++r) {
        int q = (r & 3) + 8 * (r >> 2) + 4 * hh;
        float m_own = mls[wid][q][0];   // per-row max from LDS (R20 fix)
        float Mg = fmaxf(fmaxf(mls[0][q][0], mls[1][q][0]),
                         fmaxf(mls[2][q][0], mls[3][q][0]));
        float s = exp2f(m_own - Mg);
#pragma unroll
        for (int c = 0; c < 4; ++c) {
          float v = oacc[c][r] * s;
          if (w == 0) Obuf[q][32 * c + l31] = v;
          else        Obuf[q][32 * c + l31] += v;
        }
      }
    }
    __syncthreads();
  }

  // write-out: wave wid normalizes+stores rows wid*8 .. wid*8+7
#pragma unroll
  for (int rr = 0; rr < 8; ++rr) {
    int row = wid * 8 + rr;
    float Mg = fmaxf(fmaxf(mls[0][row][0], mls[1][row][0]),
                     fmaxf(mls[2][row][0], mls[3][row][0]));
    float lt = 0.f;
#pragma unroll
    for (int w2 = 0; w2 < 4; ++w2)
      lt += exp2f(mls[w2][row][0] - Mg) * mls[w2][row][1];
    float inv = 1.0f / lt;
    float v0 = Obuf[row][lane * 2]     * inv;
    float v1 = Obuf[row][lane * 2 + 1] * inv;
    unsigned pack = (unsigned)f2bf(v0) | ((unsigned)f2bf(v1) << 16);
    *(unsigned*)&ao[(size_t)(q0 + row) * 2048 + h * 128 + lane * 2] = pack;
  }
}

// ---------------------------------------------------------------------------
extern "C" void kernel_launch(void* const* d_in, const int* in_sizes, int n_in,
                              void* d_out, int out_size, void* d_ws, size_t ws_size,
                              hipStream_t stream) {
  const float* x     = (const float*)d_in[0];   // 2048 x 2048 f32
  const float* w_qkv = (const float*)d_in[1];   // 6144 x 2048 f32
  const float* w_out = (const float*)d_in[2];   // 2048 x 2048 f32
  float* out = (float*)d_out;                   // 2048 x 2048 f32
  const int S = 2048, H = 2048, O3 = 6144;

  // workspace (u16 elems), peak 58.8 MB with aliasing:
  u16* qkv     = (u16*)d_ws;                    // S*O3 = 25.2 MB
  u16* x_bf    = qkv + (size_t)S * O3;          //  8.4 MB
  u16* wqkv_bf = x_bf + (size_t)S * H;          // 25.2 MB region
  u16* ao      = x_bf;                          // alias (x_bf dead after GEMM1)
  u16* vt2     = wqkv_bf;                       // alias: 8.4 MB
  u16* kt2     = wqkv_bf + (size_t)H * S;       // alias: 8.4 MB
  u16* wout_bf = wqkv_bf + 2 * (size_t)H * S;   // alias: 8.4 MB (= 25.2 total)

  // 1. convert x and w_qkv to bf16 (single fused launch)
  conv2_f32_bf16<<<(S * H) / 1024 + (O3 * H) / 1024, 256, 0, stream>>>(
      x, x_bf, (S * H) / 1024, w_qkv, wqkv_bf);
  // 2. qkv = x @ w_qkv^T  (M=2048, N=6144, K=2048) -- pipelined 128^2, 768 blocks
  gemm128p_bt<u16><<<(S / 128) * (O3 / 128), 256, 0, stream>>>(x_bf, wqkv_bf, qkv, S, O3, H);
  // 3. MEGA: V repack + K rope+repack + Q rope + w_out conversion, one launch
  repack_mega<<<dim3(64, 176), 256, 0, stream>>>(qkv, vt2, kt2, qkv, w_out, wout_bf);
  // 4. causal flash attention (4-wave flat blocks, LPT order) -> ao
  attn_fwd<<<dim3(64, 16), 256, 0, stream>>>(qkv, kt2, vt2, ao);
  // 5. out = ao @ w_out^T  (M=2048, N=2048, K=2048) -- pipelined 128x64, f32 out
  gemm128x64p_bt<float><<<(S / 128) * (H / 64), 256, 0, stream>>>(ao, wout_bf, out, S, H, H);
}